// Round 1
// baseline (1184.107 us; speedup 1.0000x reference)
//
#include <hip/hip_runtime.h>
#include <math.h>

// ---------------- workspace layout (float offsets) ----------------
// W1T: 243*256            = 62208
// W2T: 16384*128          = 2097152
// H  : 64*256*24*24       = 9437184   (aliased by L, PR after conv2)
// P  : 64*128*81          = 663552
// UT : 1296*8*64          = 663552
// S0/OUT0/S1/OUT1/S2 each = 44032 (contiguous)
static constexpr size_t W1T_OFF  = 0;
static constexpr size_t W2T_OFF  = 62208;
static constexpr size_t H_OFF    = 2159360;
static constexpr size_t P_OFF    = 11596544;
static constexpr size_t UT_OFF   = 12260096;
static constexpr size_t S0_OFF   = 12923648;
static constexpr size_t OUT0_OFF = 12967680;
static constexpr size_t S1_OFF   = 13011712;
static constexpr size_t OUT1_OFF = 13055744;
static constexpr size_t S2_OFF   = 13099776;   // end 13143808 floats = 52.6 MB
static constexpr size_t L_OFF    = H_OFF;                 // 1296*64*43 = 3566592 (alias of H)
static constexpr size_t PR_OFF   = H_OFF + 3566592;       // 3566592 (alias of H)

// ---------------- init: p <- bias broadcast, S0/OUT0/S1/OUT1/S2 <- 0 ------
__global__ void k_init(float* ws, const float* prim_b) {
    int g = blockIdx.x * 256 + threadIdx.x;          // grid 3452*256 = 883712 exact
    if (g < 663552) {
        int c = (g / 81) & 127;
        ws[P_OFF + g] = prim_b[c];
    } else {
        ws[S0_OFF + (g - 663552)] = 0.f;             // 5*44032 = 220160 contiguous
    }
}

// ---------------- transpose conv1_w (256,243) -> W1T[243][256] ------------
__global__ void k_tr1(float* ws, const float* w1) {
    int g = blockIdx.x * 256 + threadIdx.x;          // 243*256 = 62208 exact
    int k = g >> 8, oc = g & 255;
    ws[W1T_OFF + g] = w1[oc * 243 + k];
}

// ---------------- transpose prim_w (128,16384) -> W2T[16384][128] ---------
__global__ void k_tr2(float* ws, const float* w2) {
    __shared__ float tile[64 * 130];
    int k0 = blockIdx.x * 64;                        // 256 blocks
    int t = threadIdx.x;
    for (int j = 0; j < 32; ++j) {                   // 8192 = 64k x 128oc
        int f = j * 256 + t;
        int oc = f >> 6, kk = f & 63;
        tile[kk * 130 + oc] = w2[oc * 16384 + k0 + kk];
    }
    __syncthreads();
    for (int j = 0; j < 32; ++j) {
        int f = j * 256 + t;
        int kk = f >> 7, oc = f & 127;
        ws[W2T_OFF + (size_t)(k0 + kk) * 128 + oc] = tile[kk * 130 + oc];
    }
}

// ---------------- conv1 9x9 VALID + bias + relu -> h NCHW -----------------
__global__ __launch_bounds__(256) void k_conv1(float* ws, const float* x, const float* b1) {
    __shared__ float xs[864];                        // 3c x 9rows x 32
    int blk = blockIdx.x;                            // 64*24
    int b = blk / 24, oy = blk % 24;
    int t = threadIdx.x;
    for (int f = t; f < 864; f += 256) {
        int c = f / 288, r = (f >> 5) % 9, ix = f & 31;
        xs[f] = x[b * 3072 + c * 1024 + (oy + r) * 32 + ix];
    }
    __syncthreads();
    int oc = t;
    float acc[24];
    float bias = b1[oc];
#pragma unroll
    for (int j = 0; j < 24; ++j) acc[j] = bias;
    const float* w1t = ws + W1T_OFF;
    for (int c = 0; c < 3; ++c)
        for (int ky = 0; ky < 9; ++ky) {
            float xr[32];
            const float4* row4 = (const float4*)(xs + c * 288 + ky * 32);
#pragma unroll
            for (int q = 0; q < 8; ++q) {
                float4 v = row4[q];
                xr[q * 4] = v.x; xr[q * 4 + 1] = v.y; xr[q * 4 + 2] = v.z; xr[q * 4 + 3] = v.w;
            }
            int kbase = (c * 81 + ky * 9) * 256 + oc;
#pragma unroll
            for (int kx = 0; kx < 9; ++kx) {
                float w = w1t[kbase + kx * 256];
#pragma unroll
                for (int j = 0; j < 24; ++j) acc[j] += w * xr[j + kx];
            }
        }
    float* hp = ws + H_OFF + (size_t)((b * 256 + oc) * 24 + oy) * 24;
#pragma unroll
    for (int j = 0; j < 24; ++j) hp[j] = fmaxf(acc[j], 0.f);
}

// ---------------- conv2 8x8 stride2 VALID, split-K atomic into p ----------
__global__ __launch_bounds__(576) void k_conv2(float* ws) {
    __shared__ float hs[4608];                       // 8c x 24 x 24
    int blk = blockIdx.x;                            // 64b x 2ohalf x 4cq = 512
    int b = blk >> 3;
    int ohalf = (blk >> 2) & 1;
    int cq = blk & 3;
    int t = threadIdx.x;                             // 9oy x 64oc
    int oy = t >> 6, ocl = t & 63;
    int oc = ohalf * 64 + ocl;
    const float* hbase = ws + H_OFF + (size_t)b * 147456;
    const float* w2t = ws + W2T_OFF;
    float acc[9];
#pragma unroll
    for (int j = 0; j < 9; ++j) acc[j] = 0.f;
    for (int chunk = 0; chunk < 8; ++chunk) {
        int cbase = cq * 64 + chunk * 8;
        __syncthreads();
        for (int f = t; f < 4608; f += 576)
            hs[f] = hbase[(cbase + (f / 576)) * 576 + (f % 576)];
        __syncthreads();
        for (int cl = 0; cl < 8; ++cl) {
#pragma unroll
            for (int ky = 0; ky < 8; ++ky) {
                float xr[24];
                const float4* row4 = (const float4*)(hs + cl * 576 + (2 * oy + ky) * 24);
#pragma unroll
                for (int q = 0; q < 6; ++q) {
                    float4 v = row4[q];
                    xr[q * 4] = v.x; xr[q * 4 + 1] = v.y; xr[q * 4 + 2] = v.z; xr[q * 4 + 3] = v.w;
                }
                int kbase = ((cbase + cl) * 64 + ky * 8) * 128 + oc;
#pragma unroll
                for (int kx = 0; kx < 8; ++kx) {
                    float w = w2t[kbase + kx * 128];
#pragma unroll
                    for (int ox = 0; ox < 9; ++ox) acc[ox] += w * xr[2 * ox + kx];
                }
            }
        }
    }
    float* pp = ws + P_OFF + (size_t)(b * 128 + oc) * 81 + oy * 9;
#pragma unroll
    for (int ox = 0; ox < 9; ++ox) atomicAdd(pp + ox, acc[ox]);
}

// ---------------- squash over 8 prim caps -> u_t[n][i][b] -----------------
__global__ void k_squash_u(float* ws) {
    int g = blockIdx.x * 256 + threadIdx.x;          // 324 blocks, 82944 tasks
    if (g >= 82944) return;
    int b = g / 1296, n = g % 1296;
    int d = n / 81, s = n % 81;
    const float* p = ws + P_OFF + (size_t)b * 10368;
    float v[8]; float sn = 0.f;
#pragma unroll
    for (int i = 0; i < 8; ++i) { v[i] = p[(i * 16 + d) * 81 + s]; sn += v[i] * v[i]; }
    float f = sqrtf(sn) / (1.f + sn);
    float* ut = ws + UT_OFF;
#pragma unroll
    for (int i = 0; i < 8; ++i) ut[(n * 8 + i) * 64 + b] = v[i] * f;
}

// ------- s accumulation: sdst[b,c,o] += sum_n probs(b,n,c)*priors ---------
// probs==nullptr -> probs = 1 (iter0 raw sum; /43 folded into squash scale)
__global__ __launch_bounds__(256) void k_saccum(float* ws, const float* route_w,
                                                const float* probs, float* sdst) {
    __shared__ float wsl[10368];                     // 81n x 128(i,o) for fixed c
    int bx = blockIdx.x;                             // 43c x 16tile = 688
    int c = bx % 43, tile = bx / 43;
    int n0 = tile * 81;
    int t = threadIdx.x;
    for (int f = t; f < 10368; f += 256) {
        int row = f >> 7, col = f & 127;
        wsl[f] = route_w[((size_t)(n0 + row) * 43 + c) * 128 + col];
    }
    __syncthreads();
    int b = t & 63, og = t >> 6;
    const float* ut = ws + UT_OFF;
    float ax = 0.f, ay = 0.f, az = 0.f, aw = 0.f;
    for (int nl = 0; nl < 81; ++nl) {
        int n = n0 + nl;
        float pv = probs ? probs[((size_t)n * 43 + c) * 64 + b] : 1.0f;
#pragma unroll
        for (int i = 0; i < 8; ++i) {
            float uv = ut[(n * 8 + i) * 64 + b] * pv;
            float4 w4 = *(const float4*)(wsl + nl * 128 + i * 16 + og * 4);
            ax += uv * w4.x; ay += uv * w4.y; az += uv * w4.z; aw += uv * w4.w;
        }
    }
    float* dst = sdst + ((size_t)b * 43 + c) * 16 + og * 4;
    atomicAdd(dst + 0, ax); atomicAdd(dst + 1, ay);
    atomicAdd(dst + 2, az); atomicAdd(dst + 3, aw);
}

// ---------------- outputs = squash(s * scale) -----------------------------
__global__ void k_outsquash(const float* s, float* o, float scale) {
    int g = blockIdx.x * 256 + threadIdx.x;          // 11 blocks, 2752 tasks
    if (g >= 2752) return;
    const float4* sp = (const float4*)(s + (size_t)g * 16);
    float v[16]; float sn = 0.f;
#pragma unroll
    for (int q = 0; q < 4; ++q) {
        float4 w = sp[q];
        v[q * 4] = w.x * scale; v[q * 4 + 1] = w.y * scale;
        v[q * 4 + 2] = w.z * scale; v[q * 4 + 3] = w.w * scale;
    }
#pragma unroll
    for (int j = 0; j < 16; ++j) sn += v[j] * v[j];
    float f = sqrtf(sn) / (1.f + sn);
    float* op = o + (size_t)g * 16;
#pragma unroll
    for (int j = 0; j < 16; ++j) op[j] = v[j] * f;
}

// ---- delta pass: L[n,b,c] (+)= sum_o priors(b,n,c,o)*outv(b,c,o) ---------
__global__ __launch_bounds__(256) void k_delta(float* ws, const float* route_w,
                                               const float* outv, float* L, int add) {
    __shared__ float wt[5504];                       // [c][o][i] transposed
    int n = blockIdx.x, t = threadIdx.x;             // 1296 blocks
    for (int f = t; f < 5504; f += 256) {
        int c = f >> 7, i = (f >> 4) & 7, o = f & 15;
        wt[c * 128 + o * 8 + i] = route_w[(size_t)n * 5504 + f];
    }
    __syncthreads();
    const float* ut = ws + UT_OFF;
    for (int b = 0; b < 64; ++b) {
        float uv[8];
#pragma unroll
        for (int i = 0; i < 8; ++i) uv[i] = ut[(size_t)(n * 8 + i) * 64 + b];
#pragma unroll
        for (int rr = 0; rr < 3; ++rr) {
            int tau = t + rr * 256;                  // 688 (c,o) tasks; whole 16-groups stay active
            if (tau < 688) {
                int c = tau >> 4, o = tau & 15;
                const float4* w4 = (const float4*)(wt + c * 128 + o * 8);
                float4 a = w4[0], bb = w4[1];
                float pr = uv[0] * a.x + uv[1] * a.y + uv[2] * a.z + uv[3] * a.w
                         + uv[4] * bb.x + uv[5] * bb.y + uv[6] * bb.z + uv[7] * bb.w;
                float val = pr * outv[((size_t)b * 43 + c) * 16 + o];
                val += __shfl_xor(val, 1);
                val += __shfl_xor(val, 2);
                val += __shfl_xor(val, 4);
                val += __shfl_xor(val, 8);
                if (o == 0) {
                    size_t idx = ((size_t)n * 64 + b) * 43 + c;
                    L[idx] = add ? (L[idx] + val) : val;
                }
            }
        }
    }
}

// ---------------- softmax over c: L[n,b,c] -> P[n,c,b] --------------------
__global__ void k_softmax(const float* L, float* P) {
    int n = blockIdx.x, b = threadIdx.x;             // 1296 x 64
    const float* lp = L + ((size_t)n * 64 + b) * 43;
    float v[43]; float m = -1e30f;
#pragma unroll
    for (int c = 0; c < 43; ++c) { v[c] = lp[c]; m = fmaxf(m, v[c]); }
    float s = 0.f;
#pragma unroll
    for (int c = 0; c < 43; ++c) { v[c] = expf(v[c] - m); s += v[c]; }
    float inv = 1.f / s;
#pragma unroll
    for (int c = 0; c < 43; ++c) P[((size_t)n * 43 + c) * 64 + b] = v[c] * inv;
}

// ---------------- scores[b,c] = ||squash(s2)|| = sn/(1+sn) ----------------
__global__ void k_scores(const float* s2, float* out) {
    int g = blockIdx.x * 256 + threadIdx.x;
    if (g >= 2752) return;
    const float4* sp = (const float4*)(s2 + (size_t)g * 16);
    float sn = 0.f;
#pragma unroll
    for (int q = 0; q < 4; ++q) {
        float4 w = sp[q];
        sn += w.x * w.x + w.y * w.y + w.z * w.z + w.w * w.w;
    }
    out[g] = sn / (1.f + sn);
}

extern "C" void kernel_launch(void* const* d_in, const int* in_sizes, int n_in,
                              void* d_out, int out_size, void* d_ws, size_t ws_size,
                              hipStream_t stream) {
    const float* x  = (const float*)d_in[0];
    const float* w1 = (const float*)d_in[1];
    const float* b1 = (const float*)d_in[2];
    const float* w2 = (const float*)d_in[3];
    const float* b2 = (const float*)d_in[4];
    const float* rw = (const float*)d_in[5];
    float* ws  = (float*)d_ws;
    float* out = (float*)d_out;

    k_init    <<<3452, 256, 0, stream>>>(ws, b2);
    k_tr1     <<<243,  256, 0, stream>>>(ws, w1);
    k_tr2     <<<256,  256, 0, stream>>>(ws, w2);
    k_conv1   <<<1536, 256, 0, stream>>>(ws, x, b1);
    k_conv2   <<<512,  576, 0, stream>>>(ws);
    k_squash_u<<<324,  256, 0, stream>>>(ws);
    // iter 0: uniform probs (1/43 folded into squash scale)
    k_saccum   <<<688, 256, 0, stream>>>(ws, rw, nullptr, ws + S0_OFF);
    k_outsquash<<<11,  256, 0, stream>>>(ws + S0_OFF, ws + OUT0_OFF, 1.0f / 43.0f);
    k_delta    <<<1296,256, 0, stream>>>(ws, rw, ws + OUT0_OFF, ws + L_OFF, 0);
    // iter 1
    k_softmax  <<<1296, 64, 0, stream>>>(ws + L_OFF, ws + PR_OFF);
    k_saccum   <<<688, 256, 0, stream>>>(ws, rw, ws + PR_OFF, ws + S1_OFF);
    k_outsquash<<<11,  256, 0, stream>>>(ws + S1_OFF, ws + OUT1_OFF, 1.0f);
    k_delta    <<<1296,256, 0, stream>>>(ws, rw, ws + OUT1_OFF, ws + L_OFF, 1);
    // iter 2
    k_softmax  <<<1296, 64, 0, stream>>>(ws + L_OFF, ws + PR_OFF);
    k_saccum   <<<688, 256, 0, stream>>>(ws, rw, ws + PR_OFF, ws + S2_OFF);
    k_scores   <<<11,  256, 0, stream>>>(ws + S2_OFF, out);
}

// Round 2
// 694.525 us; speedup vs baseline: 1.7049x; 1.7049x over previous
//
#include <hip/hip_runtime.h>
#include <math.h>

// ---------------- workspace layout (float offsets) ----------------
// PK2: packed bf16 W2 fragments: 512 ksteps * 8 nt * 64 lane * 8 bf16 = 2M bf16 = 1M floats
// H  : 64*256*576 bf16 = 4.72M floats (aliased by L, PR after conv2 is consumed)
static constexpr size_t W1T_OFF  = 0;
static constexpr size_t W2T_OFF  = 62208;            // now holds PK2 (1048576 floats)
static constexpr size_t H_OFF    = 2159360;
static constexpr size_t P_OFF    = 11596544;
static constexpr size_t UT_OFF   = 12260096;
static constexpr size_t S0_OFF   = 12923648;
static constexpr size_t OUT0_OFF = 12967680;
static constexpr size_t S1_OFF   = 13011712;
static constexpr size_t OUT1_OFF = 13055744;
static constexpr size_t S2_OFF   = 13099776;   // end 13143808 floats = 52.6 MB
static constexpr size_t L_OFF    = H_OFF;                 // written AFTER H is dead
static constexpr size_t PR_OFF   = H_OFF + 3566592;

typedef __bf16 bf16x8 __attribute__((ext_vector_type(8)));
typedef float  f32x4  __attribute__((ext_vector_type(4)));

__device__ inline unsigned short f2bf(float f) {       // RNE fp32 -> bf16
    unsigned int u = __float_as_uint(f);
    u = (u + 0x7fffu + ((u >> 16) & 1u)) >> 16;
    return (unsigned short)u;
}

// ---------------- init: p <- bias broadcast, S0/OUT0/S1/OUT1/S2 <- 0 ------
__global__ void k_init(float* ws, const float* prim_b) {
    int g = blockIdx.x * 256 + threadIdx.x;          // grid 3452*256 = 883712 exact
    if (g < 663552) {
        int c = (g / 81) & 127;
        ws[P_OFF + g] = prim_b[c];
    } else {
        ws[S0_OFF + (g - 663552)] = 0.f;             // 5*44032 = 220160 contiguous
    }
}

// ---------------- transpose conv1_w (256,243) -> W1T[243][256] ------------
__global__ void k_tr1(float* ws, const float* w1) {
    int g = blockIdx.x * 256 + threadIdx.x;          // 243*256 = 62208 exact
    int k = g >> 8, oc = g & 255;
    ws[W1T_OFF + g] = w1[oc * 243 + k];
}

// ---- pack prim_w (128 x 16384 fp32) -> bf16 MFMA B-fragment order --------
// frag block g = (s*8 + nt)*64 + lane ; values j=0..7 : w2[n][k0 + quad*8 + j]
// with n = nt*16 + (lane&15), quad = lane>>4, k0 = s*32
__global__ void k_pack2(float* ws, const float* w2) {
    int g = blockIdx.x * 256 + threadIdx.x;          // 1024 blocks -> 262144 exact
    int s = g >> 9;
    int r = g & 511;
    int nt = r >> 6, lane = r & 63;
    int n = nt * 16 + (lane & 15);
    int k0 = s * 32 + (lane >> 4) * 8;
    const float4* src = (const float4*)(w2 + (size_t)n * 16384 + k0);
    float4 v0 = src[0], v1 = src[1];
    uint4 o;
    o.x = (unsigned)f2bf(v0.x) | ((unsigned)f2bf(v0.y) << 16);
    o.y = (unsigned)f2bf(v0.z) | ((unsigned)f2bf(v0.w) << 16);
    o.z = (unsigned)f2bf(v1.x) | ((unsigned)f2bf(v1.y) << 16);
    o.w = (unsigned)f2bf(v1.z) | ((unsigned)f2bf(v1.w) << 16);
    ((uint4*)(ws + W2T_OFF))[g] = o;
}

// ---------------- conv1 9x9 VALID + bias + relu -> h (bf16, NCHW) ---------
__global__ __launch_bounds__(256) void k_conv1(float* ws, const float* x, const float* b1) {
    __shared__ float xs[864];                        // 3c x 9rows x 32
    int blk = blockIdx.x;                            // 64*24
    int b = blk / 24, oy = blk % 24;
    int t = threadIdx.x;
    for (int f = t; f < 864; f += 256) {
        int c = f / 288, r = (f >> 5) % 9, ix = f & 31;
        xs[f] = x[b * 3072 + c * 1024 + (oy + r) * 32 + ix];
    }
    __syncthreads();
    int oc = t;
    float acc[24];
    float bias = b1[oc];
#pragma unroll
    for (int j = 0; j < 24; ++j) acc[j] = bias;
    const float* w1t = ws + W1T_OFF;
    for (int c = 0; c < 3; ++c)
        for (int ky = 0; ky < 9; ++ky) {
            float xr[32];
            const float4* row4 = (const float4*)(xs + c * 288 + ky * 32);
#pragma unroll
            for (int q = 0; q < 8; ++q) {
                float4 v = row4[q];
                xr[q * 4] = v.x; xr[q * 4 + 1] = v.y; xr[q * 4 + 2] = v.z; xr[q * 4 + 3] = v.w;
            }
            int kbase = (c * 81 + ky * 9) * 256 + oc;
#pragma unroll
            for (int kx = 0; kx < 9; ++kx) {
                float w = w1t[kbase + kx * 256];
#pragma unroll
                for (int j = 0; j < 24; ++j) acc[j] += w * xr[j + kx];
            }
        }
    // store bf16, packed pairs (row of 24 = 12 dwords)
    unsigned int* hp = (unsigned int*)((unsigned short*)(ws + H_OFF)
                        + ((size_t)(b * 256 + oc) * 576 + (size_t)oy * 24));
#pragma unroll
    for (int j = 0; j < 12; ++j) {
        float a0 = fmaxf(acc[2 * j], 0.f), a1 = fmaxf(acc[2 * j + 1], 0.f);
        hp[j] = (unsigned)f2bf(a0) | ((unsigned)f2bf(a1) << 16);
    }
}

// ------------- conv2 as implicit-im2col bf16 MFMA GEMM --------------------
// grid 512 = 64 b x 4 kq x 2 nh ; block 256 (4 waves)
// wave (mg,ng): 3 M-tiles (mg*3+mi), 2 N-tiles (nh*4 + ng*2 + ni)
// A[m][k]: m=p (output pos, 81 padded to 96), k = c*64 + ky*8 + kx
//          = h[b][c][2*oy+ky][2*ox+kx] -> lane frag = 8 contiguous bf16 in a row
__global__ __launch_bounds__(256) void k_conv2_mfma(float* ws) {
    __shared__ unsigned short hs[2][2304];           // 2 bufs x 4ch x 576
    int blk = blockIdx.x;
    int b  = blk >> 3;
    int kq = (blk >> 1) & 3;
    int nh = blk & 1;
    int t = threadIdx.x;
    int w = t >> 6, lane = t & 63;
    int quad = lane >> 4, m = lane & 15;
    int mg = w >> 1, ng = w & 1;

    int aoy2[3], aox[3];                             // A addressing per M-tile
#pragma unroll
    for (int mi = 0; mi < 3; ++mi) {
        int p = (mg * 3 + mi) * 16 + m;
        if (p > 80) p = 0;                           // pad rows -> junk, discarded
        aoy2[mi] = (p / 9) * 2;
        aox[mi] = p % 9;
    }

    const float4* hsg = (const float4*)((const unsigned short*)(ws + H_OFF)
                         + (size_t)(b * 256 + kq * 64) * 576);
    const uint4* wp = (const uint4*)(ws + W2T_OFF);

    f32x4 acc[3][2];
#pragma unroll
    for (int mi = 0; mi < 3; ++mi)
#pragma unroll
        for (int ni = 0; ni < 2; ++ni) acc[mi][ni] = (f32x4){0.f, 0.f, 0.f, 0.f};

    // stage 0
    ((float4*)&hs[0][0])[t] = hsg[t];
    if (t < 32) ((float4*)&hs[0][0])[256 + t] = hsg[256 + t];
    __syncthreads();

    for (int st = 0; st < 16; ++st) {
        float4 pre0, pre1;
        bool more = (st < 15);
        if (more) {
            pre0 = hsg[(st + 1) * 288 + t];
            if (t < 32) pre1 = hsg[(st + 1) * 288 + 256 + t];
        }
        const unsigned short* buf = &hs[st & 1][0];
#pragma unroll
        for (int cL = 0; cL < 4; ++cL) {
            int cg = kq * 64 + st * 4 + cL;
            const unsigned short* cbuf = buf + cL * 576;
#pragma unroll
            for (int ks = 0; ks < 2; ++ks) {
                int s = cg * 2 + ks;
                // B fragments (packed, coalesced 16B/lane)
                union { uint4 u; bf16x8 v; } bf0, bf1;
                bf0.u = wp[(size_t)(s * 8 + nh * 4 + ng * 2 + 0) * 64 + lane];
                bf1.u = wp[(size_t)(s * 8 + nh * 4 + ng * 2 + 1) * 64 + lane];
                int rowk = ks * 4 + quad;            // ky
#pragma unroll
                for (int mi = 0; mi < 3; ++mi) {
                    const unsigned int* ap =
                        (const unsigned int*)cbuf + (aoy2[mi] + rowk) * 12 + aox[mi];
                    union { unsigned int u[4]; bf16x8 v; } af;
                    af.u[0] = ap[0]; af.u[1] = ap[1]; af.u[2] = ap[2]; af.u[3] = ap[3];
                    acc[mi][0] = __builtin_amdgcn_mfma_f32_16x16x32_bf16(
                        af.v, bf0.v, acc[mi][0], 0, 0, 0);
                    acc[mi][1] = __builtin_amdgcn_mfma_f32_16x16x32_bf16(
                        af.v, bf1.v, acc[mi][1], 0, 0, 0);
                }
            }
        }
        __syncthreads();
        if (more) {
            ((float4*)&hs[(st + 1) & 1][0])[t] = pre0;
            if (t < 32) ((float4*)&hs[(st + 1) & 1][0])[256 + t] = pre1;
        }
        __syncthreads();
    }

    // epilogue: D row = quad*4+reg (= position p), col = lane&15 (= oc)
#pragma unroll
    for (int mi = 0; mi < 3; ++mi) {
#pragma unroll
        for (int ni = 0; ni < 2; ++ni) {
            int n = nh * 64 + (ng * 2 + ni) * 16 + m;
            float* pp = ws + P_OFF + ((size_t)b * 128 + n) * 81;
#pragma unroll
            for (int reg = 0; reg < 4; ++reg) {
                int p = (mg * 3 + mi) * 16 + quad * 4 + reg;
                if (p < 81) atomicAdd(pp + p, acc[mi][ni][reg]);
            }
        }
    }
}

// ---------------- squash over 8 prim caps -> u_t[n][i][b] -----------------
__global__ void k_squash_u(float* ws) {
    int g = blockIdx.x * 256 + threadIdx.x;          // 324 blocks, 82944 tasks
    if (g >= 82944) return;
    int b = g / 1296, n = g % 1296;
    int d = n / 81, s = n % 81;
    const float* p = ws + P_OFF + (size_t)b * 10368;
    float v[8]; float sn = 0.f;
#pragma unroll
    for (int i = 0; i < 8; ++i) { v[i] = p[(i * 16 + d) * 81 + s]; sn += v[i] * v[i]; }
    float f = sqrtf(sn) / (1.f + sn);
    float* ut = ws + UT_OFF;
#pragma unroll
    for (int i = 0; i < 8; ++i) ut[(n * 8 + i) * 64 + b] = v[i] * f;
}

// ------- s accumulation: sdst[b,c,o] += sum_n probs(b,n,c)*priors ---------
__global__ __launch_bounds__(256) void k_saccum(float* ws, const float* route_w,
                                                const float* probs, float* sdst) {
    __shared__ float wsl[10368];                     // 81n x 128(i,o) for fixed c
    int bx = blockIdx.x;                             // 43c x 16tile = 688
    int c = bx % 43, tile = bx / 43;
    int n0 = tile * 81;
    int t = threadIdx.x;
    for (int f = t; f < 10368; f += 256) {
        int row = f >> 7, col = f & 127;
        wsl[f] = route_w[((size_t)(n0 + row) * 43 + c) * 128 + col];
    }
    __syncthreads();
    int b = t & 63, og = t >> 6;
    const float* ut = ws + UT_OFF;
    float ax = 0.f, ay = 0.f, az = 0.f, aw = 0.f;
    for (int nl = 0; nl < 81; ++nl) {
        int n = n0 + nl;
        float pv = probs ? probs[((size_t)n * 43 + c) * 64 + b] : 1.0f;
#pragma unroll
        for (int i = 0; i < 8; ++i) {
            float uv = ut[(n * 8 + i) * 64 + b] * pv;
            float4 w4 = *(const float4*)(wsl + nl * 128 + i * 16 + og * 4);
            ax += uv * w4.x; ay += uv * w4.y; az += uv * w4.z; aw += uv * w4.w;
        }
    }
    float* dst = sdst + ((size_t)b * 43 + c) * 16 + og * 4;
    atomicAdd(dst + 0, ax); atomicAdd(dst + 1, ay);
    atomicAdd(dst + 2, az); atomicAdd(dst + 3, aw);
}

// ---------------- outputs = squash(s * scale) -----------------------------
__global__ void k_outsquash(const float* s, float* o, float scale) {
    int g = blockIdx.x * 256 + threadIdx.x;          // 11 blocks, 2752 tasks
    if (g >= 2752) return;
    const float4* sp = (const float4*)(s + (size_t)g * 16);
    float v[16]; float sn = 0.f;
#pragma unroll
    for (int q = 0; q < 4; ++q) {
        float4 w = sp[q];
        v[q * 4] = w.x * scale; v[q * 4 + 1] = w.y * scale;
        v[q * 4 + 2] = w.z * scale; v[q * 4 + 3] = w.w * scale;
    }
#pragma unroll
    for (int j = 0; j < 16; ++j) sn += v[j] * v[j];
    float f = sqrtf(sn) / (1.f + sn);
    float* op = o + (size_t)g * 16;
#pragma unroll
    for (int j = 0; j < 16; ++j) op[j] = v[j] * f;
}

// ---- delta pass: L[n,b,c] (+)= sum_o priors(b,n,c,o)*outv(b,c,o) ---------
__global__ __launch_bounds__(256) void k_delta(float* ws, const float* route_w,
                                               const float* outv, float* L, int add) {
    __shared__ float wt[5504];                       // [c][o][i] transposed
    int n = blockIdx.x, t = threadIdx.x;             // 1296 blocks
    for (int f = t; f < 5504; f += 256) {
        int c = f >> 7, i = (f >> 4) & 7, o = f & 15;
        wt[c * 128 + o * 8 + i] = route_w[(size_t)n * 5504 + f];
    }
    __syncthreads();
    const float* ut = ws + UT_OFF;
    for (int b = 0; b < 64; ++b) {
        float uv[8];
#pragma unroll
        for (int i = 0; i < 8; ++i) uv[i] = ut[(size_t)(n * 8 + i) * 64 + b];
#pragma unroll
        for (int rr = 0; rr < 3; ++rr) {
            int tau = t + rr * 256;                  // 688 (c,o) tasks
            if (tau < 688) {
                int c = tau >> 4, o = tau & 15;
                const float4* w4 = (const float4*)(wt + c * 128 + o * 8);
                float4 a = w4[0], bb = w4[1];
                float pr = uv[0] * a.x + uv[1] * a.y + uv[2] * a.z + uv[3] * a.w
                         + uv[4] * bb.x + uv[5] * bb.y + uv[6] * bb.z + uv[7] * bb.w;
                float val = pr * outv[((size_t)b * 43 + c) * 16 + o];
                val += __shfl_xor(val, 1);
                val += __shfl_xor(val, 2);
                val += __shfl_xor(val, 4);
                val += __shfl_xor(val, 8);
                if (o == 0) {
                    size_t idx = ((size_t)n * 64 + b) * 43 + c;
                    L[idx] = add ? (L[idx] + val) : val;
                }
            }
        }
    }
}

// ---------------- softmax over c: L[n,b,c] -> P[n,c,b] --------------------
__global__ void k_softmax(const float* L, float* P) {
    int n = blockIdx.x, b = threadIdx.x;             // 1296 x 64
    const float* lp = L + ((size_t)n * 64 + b) * 43;
    float v[43]; float m = -1e30f;
#pragma unroll
    for (int c = 0; c < 43; ++c) { v[c] = lp[c]; m = fmaxf(m, v[c]); }
    float s = 0.f;
#pragma unroll
    for (int c = 0; c < 43; ++c) { v[c] = expf(v[c] - m); s += v[c]; }
    float inv = 1.f / s;
#pragma unroll
    for (int c = 0; c < 43; ++c) P[((size_t)n * 43 + c) * 64 + b] = v[c] * inv;
}

// ---------------- scores[b,c] = ||squash(s2)|| = sn/(1+sn) ----------------
__global__ void k_scores(const float* s2, float* out) {
    int g = blockIdx.x * 256 + threadIdx.x;
    if (g >= 2752) return;
    const float4* sp = (const float4*)(s2 + (size_t)g * 16);
    float sn = 0.f;
#pragma unroll
    for (int q = 0; q < 4; ++q) {
        float4 w = sp[q];
        sn += w.x * w.x + w.y * w.y + w.z * w.z + w.w * w.w;
    }
    out[g] = sn / (1.f + sn);
}

extern "C" void kernel_launch(void* const* d_in, const int* in_sizes, int n_in,
                              void* d_out, int out_size, void* d_ws, size_t ws_size,
                              hipStream_t stream) {
    const float* x  = (const float*)d_in[0];
    const float* w1 = (const float*)d_in[1];
    const float* b1 = (const float*)d_in[2];
    const float* w2 = (const float*)d_in[3];
    const float* b2 = (const float*)d_in[4];
    const float* rw = (const float*)d_in[5];
    float* ws  = (float*)d_ws;
    float* out = (float*)d_out;

    k_init      <<<3452, 256, 0, stream>>>(ws, b2);
    k_tr1       <<<243,  256, 0, stream>>>(ws, w1);
    k_pack2     <<<1024, 256, 0, stream>>>(ws, w2);
    k_conv1     <<<1536, 256, 0, stream>>>(ws, x, b1);
    k_conv2_mfma<<<512,  256, 0, stream>>>(ws);
    k_squash_u  <<<324,  256, 0, stream>>>(ws);
    // iter 0: uniform probs (1/43 folded into squash scale)
    k_saccum   <<<688, 256, 0, stream>>>(ws, rw, nullptr, ws + S0_OFF);
    k_outsquash<<<11,  256, 0, stream>>>(ws + S0_OFF, ws + OUT0_OFF, 1.0f / 43.0f);
    k_delta    <<<1296,256, 0, stream>>>(ws, rw, ws + OUT0_OFF, ws + L_OFF, 0);
    // iter 1
    k_softmax  <<<1296, 64, 0, stream>>>(ws + L_OFF, ws + PR_OFF);
    k_saccum   <<<688, 256, 0, stream>>>(ws, rw, ws + PR_OFF, ws + S1_OFF);
    k_outsquash<<<11,  256, 0, stream>>>(ws + S1_OFF, ws + OUT1_OFF, 1.0f);
    k_delta    <<<1296,256, 0, stream>>>(ws, rw, ws + OUT1_OFF, ws + L_OFF, 1);
    // iter 2
    k_softmax  <<<1296, 64, 0, stream>>>(ws + L_OFF, ws + PR_OFF);
    k_saccum   <<<688, 256, 0, stream>>>(ws, rw, ws + PR_OFF, ws + S2_OFF);
    k_scores   <<<11,  256, 0, stream>>>(ws + S2_OFF, out);
}

// Round 3
// 577.775 us; speedup vs baseline: 2.0494x; 1.2021x over previous
//
#include <hip/hip_runtime.h>
#include <math.h>

// ---------------- workspace layout (float offsets) ----------------
static constexpr size_t W1T_OFF  = 0;
static constexpr size_t W2T_OFF  = 62208;            // packed bf16 W2 frags (1048576 floats)
static constexpr size_t H_OFF    = 2159360;
static constexpr size_t P_OFF    = 11596544;
static constexpr size_t UT_OFF   = 12260096;
static constexpr size_t S0_OFF   = 12923648;
static constexpr size_t OUT0_OFF = 12967680;         // OUTT iter0: [c][o][b]
static constexpr size_t S1_OFF   = 13011712;
static constexpr size_t OUT1_OFF = 13055744;         // OUTT iter1
static constexpr size_t S2_OFF   = 13099776;   // end 13143808 floats = 52.6 MB
static constexpr size_t L_OFF    = H_OFF;            // L[n][c][b] 1296*43*64 (alias of dead H)
static constexpr size_t PR_OFF   = H_OFF + 3566592;  // P[n][c][b]

typedef __bf16 bf16x8 __attribute__((ext_vector_type(8)));
typedef float  f32x4  __attribute__((ext_vector_type(4)));

__device__ inline unsigned short f2bf(float f) {       // RNE fp32 -> bf16
    unsigned int u = __float_as_uint(f);
    u = (u + 0x7fffu + ((u >> 16) & 1u)) >> 16;
    return (unsigned short)u;
}

// ---------------- init: p <- bias broadcast, S0/OUT0/S1/OUT1/S2 <- 0 ------
__global__ void k_init(float* ws, const float* prim_b) {
    int g = blockIdx.x * 256 + threadIdx.x;          // grid 3452*256 = 883712 exact
    if (g < 663552) {
        int c = (g / 81) & 127;
        ws[P_OFF + g] = prim_b[c];
    } else {
        ws[S0_OFF + (g - 663552)] = 0.f;             // 5*44032 = 220160 contiguous
    }
}

// ---------------- transpose conv1_w (256,243) -> W1T[243][256] ------------
__global__ void k_tr1(float* ws, const float* w1) {
    int g = blockIdx.x * 256 + threadIdx.x;          // 243*256 = 62208 exact
    int k = g >> 8, oc = g & 255;
    ws[W1T_OFF + g] = w1[oc * 243 + k];
}

// ---- pack prim_w (128 x 16384 fp32) -> bf16 MFMA B-fragment order --------
__global__ void k_pack2(float* ws, const float* w2) {
    int g = blockIdx.x * 256 + threadIdx.x;          // 1024 blocks -> 262144 exact
    int s = g >> 9;
    int r = g & 511;
    int nt = r >> 6, lane = r & 63;
    int n = nt * 16 + (lane & 15);
    int k0 = s * 32 + (lane >> 4) * 8;
    const float4* src = (const float4*)(w2 + (size_t)n * 16384 + k0);
    float4 v0 = src[0], v1 = src[1];
    uint4 o;
    o.x = (unsigned)f2bf(v0.x) | ((unsigned)f2bf(v0.y) << 16);
    o.y = (unsigned)f2bf(v0.z) | ((unsigned)f2bf(v0.w) << 16);
    o.z = (unsigned)f2bf(v1.x) | ((unsigned)f2bf(v1.y) << 16);
    o.w = (unsigned)f2bf(v1.z) | ((unsigned)f2bf(v1.w) << 16);
    ((uint4*)(ws + W2T_OFF))[g] = o;
}

// ---------------- conv1 9x9 VALID + bias + relu -> h (bf16, NCHW) ---------
__global__ __launch_bounds__(256) void k_conv1(float* ws, const float* x, const float* b1) {
    __shared__ float xs[864];                        // 3c x 9rows x 32
    int blk = blockIdx.x;                            // 64*24
    int b = blk / 24, oy = blk % 24;
    int t = threadIdx.x;
    for (int f = t; f < 864; f += 256) {
        int c = f / 288, r = (f >> 5) % 9, ix = f & 31;
        xs[f] = x[b * 3072 + c * 1024 + (oy + r) * 32 + ix];
    }
    __syncthreads();
    int oc = t;
    float acc[24];
    float bias = b1[oc];
#pragma unroll
    for (int j = 0; j < 24; ++j) acc[j] = bias;
    const float* w1t = ws + W1T_OFF;
    for (int c = 0; c < 3; ++c)
        for (int ky = 0; ky < 9; ++ky) {
            float xr[32];
            const float4* row4 = (const float4*)(xs + c * 288 + ky * 32);
#pragma unroll
            for (int q = 0; q < 8; ++q) {
                float4 v = row4[q];
                xr[q * 4] = v.x; xr[q * 4 + 1] = v.y; xr[q * 4 + 2] = v.z; xr[q * 4 + 3] = v.w;
            }
            int kbase = (c * 81 + ky * 9) * 256 + oc;
#pragma unroll
            for (int kx = 0; kx < 9; ++kx) {
                float w = w1t[kbase + kx * 256];
#pragma unroll
                for (int j = 0; j < 24; ++j) acc[j] += w * xr[j + kx];
            }
        }
    unsigned int* hp = (unsigned int*)((unsigned short*)(ws + H_OFF)
                        + ((size_t)(b * 256 + oc) * 576 + (size_t)oy * 24));
#pragma unroll
    for (int j = 0; j < 12; ++j) {
        float a0 = fmaxf(acc[2 * j], 0.f), a1 = fmaxf(acc[2 * j + 1], 0.f);
        hp[j] = (unsigned)f2bf(a0) | ((unsigned)f2bf(a1) << 16);
    }
}

// ------------- conv2 as implicit-im2col bf16 MFMA GEMM --------------------
__global__ __launch_bounds__(256) void k_conv2_mfma(float* ws) {
    __shared__ unsigned short hs[2][2304];           // 2 bufs x 4ch x 576
    int blk = blockIdx.x;
    int b  = blk >> 3;
    int kq = (blk >> 1) & 3;
    int nh = blk & 1;
    int t = threadIdx.x;
    int w = t >> 6, lane = t & 63;
    int quad = lane >> 4, m = lane & 15;
    int mg = w >> 1, ng = w & 1;

    int aoy2[3], aox[3];
#pragma unroll
    for (int mi = 0; mi < 3; ++mi) {
        int p = (mg * 3 + mi) * 16 + m;
        if (p > 80) p = 0;
        aoy2[mi] = (p / 9) * 2;
        aox[mi] = p % 9;
    }

    const float4* hsg = (const float4*)((const unsigned short*)(ws + H_OFF)
                         + (size_t)(b * 256 + kq * 64) * 576);
    const uint4* wp = (const uint4*)(ws + W2T_OFF);

    f32x4 acc[3][2];
#pragma unroll
    for (int mi = 0; mi < 3; ++mi)
#pragma unroll
        for (int ni = 0; ni < 2; ++ni) acc[mi][ni] = (f32x4){0.f, 0.f, 0.f, 0.f};

    ((float4*)&hs[0][0])[t] = hsg[t];
    if (t < 32) ((float4*)&hs[0][0])[256 + t] = hsg[256 + t];
    __syncthreads();

    for (int st = 0; st < 16; ++st) {
        float4 pre0, pre1;
        bool more = (st < 15);
        if (more) {
            pre0 = hsg[(st + 1) * 288 + t];
            if (t < 32) pre1 = hsg[(st + 1) * 288 + 256 + t];
        }
        const unsigned short* buf = &hs[st & 1][0];
#pragma unroll
        for (int cL = 0; cL < 4; ++cL) {
            const unsigned short* cbuf = buf + cL * 576;
            int cg = kq * 64 + st * 4 + cL;
#pragma unroll
            for (int ks = 0; ks < 2; ++ks) {
                int s = cg * 2 + ks;
                union { uint4 u; bf16x8 v; } bf0, bf1;
                bf0.u = wp[(size_t)(s * 8 + nh * 4 + ng * 2 + 0) * 64 + lane];
                bf1.u = wp[(size_t)(s * 8 + nh * 4 + ng * 2 + 1) * 64 + lane];
                int rowk = ks * 4 + quad;
#pragma unroll
                for (int mi = 0; mi < 3; ++mi) {
                    const unsigned int* ap =
                        (const unsigned int*)cbuf + (aoy2[mi] + rowk) * 12 + aox[mi];
                    union { unsigned int u[4]; bf16x8 v; } af;
                    af.u[0] = ap[0]; af.u[1] = ap[1]; af.u[2] = ap[2]; af.u[3] = ap[3];
                    acc[mi][0] = __builtin_amdgcn_mfma_f32_16x16x32_bf16(
                        af.v, bf0.v, acc[mi][0], 0, 0, 0);
                    acc[mi][1] = __builtin_amdgcn_mfma_f32_16x16x32_bf16(
                        af.v, bf1.v, acc[mi][1], 0, 0, 0);
                }
            }
        }
        __syncthreads();
        if (more) {
            ((float4*)&hs[(st + 1) & 1][0])[t] = pre0;
            if (t < 32) ((float4*)&hs[(st + 1) & 1][0])[256 + t] = pre1;
        }
        __syncthreads();
    }

#pragma unroll
    for (int mi = 0; mi < 3; ++mi) {
#pragma unroll
        for (int ni = 0; ni < 2; ++ni) {
            int n = nh * 64 + (ng * 2 + ni) * 16 + m;
            float* pp = ws + P_OFF + ((size_t)b * 128 + n) * 81;
#pragma unroll
            for (int reg = 0; reg < 4; ++reg) {
                int p = (mg * 3 + mi) * 16 + quad * 4 + reg;
                if (p < 81) atomicAdd(pp + p, acc[mi][ni][reg]);
            }
        }
    }
}

// ---------------- squash over 8 prim caps -> u_t[n][i][b] -----------------
__global__ void k_squash_u(float* ws) {
    int g = blockIdx.x * 256 + threadIdx.x;          // 324 blocks, 82944 tasks
    if (g >= 82944) return;
    int b = g / 1296, n = g % 1296;
    int d = n / 81, s = n % 81;
    const float* p = ws + P_OFF + (size_t)b * 10368;
    float v[8]; float sn = 0.f;
#pragma unroll
    for (int i = 0; i < 8; ++i) { v[i] = p[(i * 16 + d) * 81 + s]; sn += v[i] * v[i]; }
    float f = sqrtf(sn) / (1.f + sn);
    float* ut = ws + UT_OFF;
#pragma unroll
    for (int i = 0; i < 8; ++i) ut[(n * 8 + i) * 64 + b] = v[i] * f;
}

// ------- s accumulation: sdst[b,c,o] += sum_n probs(n,c,b)*priors ---------
__global__ __launch_bounds__(256) void k_saccum(float* ws, const float* route_w,
                                                const float* probs, float* sdst) {
    __shared__ float wsl[10368];                     // 81n x 128(i,o) for fixed c
    int bx = blockIdx.x;                             // 43c x 16tile = 688
    int c = bx % 43, tile = bx / 43;
    int n0 = tile * 81;
    int t = threadIdx.x;
    for (int f = t; f < 10368; f += 256) {
        int row = f >> 7, col = f & 127;
        wsl[f] = route_w[((size_t)(n0 + row) * 43 + c) * 128 + col];
    }
    __syncthreads();
    int b = t & 63, og = t >> 6;
    const float* ut = ws + UT_OFF;
    float ax = 0.f, ay = 0.f, az = 0.f, aw = 0.f;
    for (int nl = 0; nl < 81; ++nl) {
        int n = n0 + nl;
        float pv = probs ? probs[((size_t)n * 43 + c) * 64 + b] : 1.0f;
#pragma unroll
        for (int i = 0; i < 8; ++i) {
            float uv = ut[(n * 8 + i) * 64 + b] * pv;
            float4 w4 = *(const float4*)(wsl + nl * 128 + i * 16 + og * 4);
            ax += uv * w4.x; ay += uv * w4.y; az += uv * w4.z; aw += uv * w4.w;
        }
    }
    float* dst = sdst + ((size_t)b * 43 + c) * 16 + og * 4;
    atomicAdd(dst + 0, ax); atomicAdd(dst + 1, ay);
    atomicAdd(dst + 2, az); atomicAdd(dst + 3, aw);
}

// -------- outputs = squash(s * scale), written transposed OUTT[c][o][b] ---
__global__ void k_outsquash(const float* s, float* ot, float scale) {
    int g = blockIdx.x * 256 + threadIdx.x;          // 11 blocks, 2752 tasks
    if (g >= 2752) return;
    int b = g / 43, c = g % 43;
    const float4* sp = (const float4*)(s + (size_t)g * 16);
    float v[16]; float sn = 0.f;
#pragma unroll
    for (int q = 0; q < 4; ++q) {
        float4 w = sp[q];
        v[q * 4] = w.x * scale; v[q * 4 + 1] = w.y * scale;
        v[q * 4 + 2] = w.z * scale; v[q * 4 + 3] = w.w * scale;
    }
#pragma unroll
    for (int j = 0; j < 16; ++j) sn += v[j] * v[j];
    float f = sqrtf(sn) / (1.f + sn);
#pragma unroll
    for (int j = 0; j < 16; ++j) ot[(size_t)(c * 16 + j) * 64 + b] = v[j] * f;
}

// ---- delta pass: L[n,c,b] (+)= sum_o priors(b,n,c,o)*outt(c,o,b) ---------
// block = n; thread = (b, cg); cg wave-uniform -> W reads are LDS broadcasts
__global__ __launch_bounds__(256) void k_delta(float* ws, const float* route_w,
                                               const float* outt, float* L, int add) {
    __shared__ float wn[5504];                       // route_w[n] natural [c][i][o]
    __shared__ float us[512];                        // u[i][b]
    int n = blockIdx.x, t = threadIdx.x;             // 1296 blocks
    const float4* src = (const float4*)(route_w + (size_t)n * 5504);
    float4* dst4 = (float4*)wn;
    for (int f = t; f < 1376; f += 256) dst4[f] = src[f];
    const float* utn = ws + UT_OFF + (size_t)n * 512;
    us[t] = utn[t];
    us[t + 256] = utn[t + 256];
    __syncthreads();
    int b = t & 63, cg = t >> 6;
    float u[8];
#pragma unroll
    for (int i = 0; i < 8; ++i) u[i] = us[i * 64 + b];
    int c0 = cg * 11;
    int c1 = c0 + 11; if (c1 > 43) c1 = 43;
    for (int c = c0; c < c1; ++c) {
        float4 p0 = {0,0,0,0}, p1 = {0,0,0,0}, p2 = {0,0,0,0}, p3 = {0,0,0,0};
        const float4* wc = (const float4*)(wn + c * 128);
#pragma unroll
        for (int i = 0; i < 8; ++i) {
            float ui = u[i];
            float4 w0 = wc[i * 4 + 0], w1 = wc[i * 4 + 1],
                   w2 = wc[i * 4 + 2], w3 = wc[i * 4 + 3];
            p0.x += ui * w0.x; p0.y += ui * w0.y; p0.z += ui * w0.z; p0.w += ui * w0.w;
            p1.x += ui * w1.x; p1.y += ui * w1.y; p1.z += ui * w1.z; p1.w += ui * w1.w;
            p2.x += ui * w2.x; p2.y += ui * w2.y; p2.z += ui * w2.z; p2.w += ui * w2.w;
            p3.x += ui * w3.x; p3.y += ui * w3.y; p3.z += ui * w3.z; p3.w += ui * w3.w;
        }
        const float* ov = outt + (size_t)c * 1024 + b;   // OUTT[c][o][b]
        float val = p0.x * ov[0]      + p0.y * ov[64]   + p0.z * ov[128]  + p0.w * ov[192]
                  + p1.x * ov[256]    + p1.y * ov[320]  + p1.z * ov[384]  + p1.w * ov[448]
                  + p2.x * ov[512]    + p2.y * ov[576]  + p2.z * ov[640]  + p2.w * ov[704]
                  + p3.x * ov[768]    + p3.y * ov[832]  + p3.z * ov[896]  + p3.w * ov[960];
        size_t idx = ((size_t)n * 43 + c) * 64 + b;      // L[n][c][b] coalesced
        L[idx] = add ? (L[idx] + val) : val;
    }
}

// ------------- softmax over c: L[n,c,b] -> P[n,c,b] -----------------------
__global__ void k_softmax(const float* L, float* P) {
    int g = blockIdx.x * 256 + threadIdx.x;          // 324 blocks = 82944 = 1296n x 64b
    int n = g >> 6, b = g & 63;
    const float* lp = L + (size_t)n * 2752 + b;
    float v[43]; float m = -1e30f;
#pragma unroll
    for (int c = 0; c < 43; ++c) { v[c] = lp[c * 64]; m = fmaxf(m, v[c]); }
    float s = 0.f;
#pragma unroll
    for (int c = 0; c < 43; ++c) { v[c] = __expf(v[c] - m); s += v[c]; }
    float inv = 1.f / s;
    float* pp = P + (size_t)n * 2752 + b;
#pragma unroll
    for (int c = 0; c < 43; ++c) pp[c * 64] = v[c] * inv;
}

// ---------------- scores[b,c] = ||squash(s2)|| = sn/(1+sn) ----------------
__global__ void k_scores(const float* s2, float* out) {
    int g = blockIdx.x * 256 + threadIdx.x;
    if (g >= 2752) return;
    const float4* sp = (const float4*)(s2 + (size_t)g * 16);
    float sn = 0.f;
#pragma unroll
    for (int q = 0; q < 4; ++q) {
        float4 w = sp[q];
        sn += w.x * w.x + w.y * w.y + w.z * w.z + w.w * w.w;
    }
    out[g] = sn / (1.f + sn);
}

extern "C" void kernel_launch(void* const* d_in, const int* in_sizes, int n_in,
                              void* d_out, int out_size, void* d_ws, size_t ws_size,
                              hipStream_t stream) {
    const float* x  = (const float*)d_in[0];
    const float* w1 = (const float*)d_in[1];
    const float* b1 = (const float*)d_in[2];
    const float* w2 = (const float*)d_in[3];
    const float* b2 = (const float*)d_in[4];
    const float* rw = (const float*)d_in[5];
    float* ws  = (float*)d_ws;
    float* out = (float*)d_out;

    k_init      <<<3452, 256, 0, stream>>>(ws, b2);
    k_tr1       <<<243,  256, 0, stream>>>(ws, w1);
    k_pack2     <<<1024, 256, 0, stream>>>(ws, w2);
    k_conv1     <<<1536, 256, 0, stream>>>(ws, x, b1);
    k_conv2_mfma<<<512,  256, 0, stream>>>(ws);
    k_squash_u  <<<324,  256, 0, stream>>>(ws);
    // iter 0: uniform probs (1/43 folded into squash scale)
    k_saccum   <<<688, 256, 0, stream>>>(ws, rw, nullptr, ws + S0_OFF);
    k_outsquash<<<11,  256, 0, stream>>>(ws + S0_OFF, ws + OUT0_OFF, 1.0f / 43.0f);
    k_delta    <<<1296,256, 0, stream>>>(ws, rw, ws + OUT0_OFF, ws + L_OFF, 0);
    // iter 1
    k_softmax  <<<324, 256, 0, stream>>>(ws + L_OFF, ws + PR_OFF);
    k_saccum   <<<688, 256, 0, stream>>>(ws, rw, ws + PR_OFF, ws + S1_OFF);
    k_outsquash<<<11,  256, 0, stream>>>(ws + S1_OFF, ws + OUT1_OFF, 1.0f);
    k_delta    <<<1296,256, 0, stream>>>(ws, rw, ws + OUT1_OFF, ws + L_OFF, 1);
    // iter 2
    k_softmax  <<<324, 256, 0, stream>>>(ws + L_OFF, ws + PR_OFF);
    k_saccum   <<<688, 256, 0, stream>>>(ws, rw, ws + PR_OFF, ws + S2_OFF);
    k_scores   <<<11,  256, 0, stream>>>(ws + S2_OFF, out);
}

// Round 4
// 495.835 us; speedup vs baseline: 2.3881x; 1.1653x over previous
//
#include <hip/hip_runtime.h>
#include <math.h>

// ---------------- workspace layout (float offsets) ----------------
static constexpr size_t W1T_OFF  = 0;
static constexpr size_t W2T_OFF  = 62208;            // packed bf16 W2 frags (1048576 floats)
static constexpr size_t H_OFF    = 2159360;          // h bf16: 4718592 floats used
static constexpr size_t PPART_OFF= H_OFF + 4718592;  // P partials [kq][b][p=81][n=128] = 5308416 floats
static constexpr size_t UT_OFF   = 12260096;
static constexpr size_t S0_OFF   = 12923648;
static constexpr size_t OUT0_OFF = 12967680;         // OUTT iter0: [c][o][b]
static constexpr size_t S1_OFF   = 13011712;
static constexpr size_t OUT1_OFF = 13055744;         // OUTT iter1
static constexpr size_t S2_OFF   = 13099776;   // end 13143808 floats = 52.6 MB
static constexpr size_t L_OFF    = H_OFF;            // L[n][c][b] (alias of dead H)
static constexpr size_t PR_OFF   = H_OFF + 3566592;  // P[n][c][b] -- NOTE: overlaps PPART (dead by then)

typedef __bf16 bf16x8 __attribute__((ext_vector_type(8)));
typedef float  f32x4  __attribute__((ext_vector_type(4)));

__device__ inline unsigned short f2bf(float f) {       // RNE fp32 -> bf16
    unsigned int u = __float_as_uint(f);
    u = (u + 0x7fffu + ((u >> 16) & 1u)) >> 16;
    return (unsigned short)u;
}

// ---------------- init: S0/OUT0/S1/OUT1/S2 <- 0 ---------------------------
__global__ void k_init(float* ws) {
    int g = blockIdx.x * 256 + threadIdx.x;          // 860*256 = 220160 exact
    ws[S0_OFF + g] = 0.f;
}

// ---------------- transpose conv1_w (256,243) -> W1T[243][256] ------------
__global__ void k_tr1(float* ws, const float* w1) {
    int g = blockIdx.x * 256 + threadIdx.x;          // 243*256 = 62208 exact
    int k = g >> 8, oc = g & 255;
    ws[W1T_OFF + g] = w1[oc * 243 + k];
}

// ---- pack prim_w (128 x 16384 fp32) -> bf16 MFMA B-fragment order --------
__global__ void k_pack2(float* ws, const float* w2) {
    int g = blockIdx.x * 256 + threadIdx.x;          // 1024 blocks -> 262144 exact
    int s = g >> 9;
    int r = g & 511;
    int nt = r >> 6, lane = r & 63;
    int n = nt * 16 + (lane & 15);
    int k0 = s * 32 + (lane >> 4) * 8;
    const float4* src = (const float4*)(w2 + (size_t)n * 16384 + k0);
    float4 v0 = src[0], v1 = src[1];
    uint4 o;
    o.x = (unsigned)f2bf(v0.x) | ((unsigned)f2bf(v0.y) << 16);
    o.y = (unsigned)f2bf(v0.z) | ((unsigned)f2bf(v0.w) << 16);
    o.z = (unsigned)f2bf(v1.x) | ((unsigned)f2bf(v1.y) << 16);
    o.w = (unsigned)f2bf(v1.z) | ((unsigned)f2bf(v1.w) << 16);
    ((uint4*)(ws + W2T_OFF))[g] = o;
}

// ---------------- conv1 9x9 VALID + bias + relu -> h (bf16, NCHW) ---------
__global__ __launch_bounds__(256) void k_conv1(float* ws, const float* x, const float* b1) {
    __shared__ float xs[864];                        // 3c x 9rows x 32
    int blk = blockIdx.x;                            // 64*24
    int b = blk / 24, oy = blk % 24;
    int t = threadIdx.x;
    for (int f = t; f < 864; f += 256) {
        int c = f / 288, r = (f >> 5) % 9, ix = f & 31;
        xs[f] = x[b * 3072 + c * 1024 + (oy + r) * 32 + ix];
    }
    __syncthreads();
    int oc = t;
    float acc[24];
    float bias = b1[oc];
#pragma unroll
    for (int j = 0; j < 24; ++j) acc[j] = bias;
    const float* w1t = ws + W1T_OFF;
    for (int c = 0; c < 3; ++c)
        for (int ky = 0; ky < 9; ++ky) {
            float xr[32];
            const float4* row4 = (const float4*)(xs + c * 288 + ky * 32);
#pragma unroll
            for (int q = 0; q < 8; ++q) {
                float4 v = row4[q];
                xr[q * 4] = v.x; xr[q * 4 + 1] = v.y; xr[q * 4 + 2] = v.z; xr[q * 4 + 3] = v.w;
            }
            int kbase = (c * 81 + ky * 9) * 256 + oc;
#pragma unroll
            for (int kx = 0; kx < 9; ++kx) {
                float w = w1t[kbase + kx * 256];
#pragma unroll
                for (int j = 0; j < 24; ++j) acc[j] += w * xr[j + kx];
            }
        }
    unsigned int* hp = (unsigned int*)((unsigned short*)(ws + H_OFF)
                        + ((size_t)(b * 256 + oc) * 576 + (size_t)oy * 24));
#pragma unroll
    for (int j = 0; j < 12; ++j) {
        float a0 = fmaxf(acc[2 * j], 0.f), a1 = fmaxf(acc[2 * j + 1], 0.f);
        hp[j] = (unsigned)f2bf(a0) | ((unsigned)f2bf(a1) << 16);
    }
}

// ------------- conv2 as implicit-im2col bf16 MFMA GEMM --------------------
// grid 1024 = 64 b x 8 kq x 2 nh ; block 256 (4 waves), 4 blocks/CU target
// 32 channels per block, 8 stages x 4 channels; B prefetched 1 cL-group ahead;
// partial tile stored (no atomics) to P_part[kq][b][p][n].
__global__ __launch_bounds__(256, 4) void k_conv2_mfma(float* ws) {
    __shared__ unsigned short hs[2][2304];           // 2 bufs x 4ch x 576
    int blk = blockIdx.x;
    int b  = blk >> 4;
    int kq = (blk >> 1) & 7;
    int nh = blk & 1;
    int t = threadIdx.x;
    int w = t >> 6, lane = t & 63;
    int quad = lane >> 4, m = lane & 15;
    int mg = w >> 1, ng = w & 1;

    int aoy2[3], aox[3];
#pragma unroll
    for (int mi = 0; mi < 3; ++mi) {
        int p = (mg * 3 + mi) * 16 + m;
        if (p > 80) p = 0;
        aoy2[mi] = (p / 9) * 2;
        aox[mi] = p % 9;
    }

    const float4* hsg = (const float4*)((const unsigned short*)(ws + H_OFF)
                         + (size_t)(b * 256 + kq * 32) * 576);
    const uint4* wp = (const uint4*)(ws + W2T_OFF);
    int ntb = nh * 4 + ng * 2;                       // base fragment column group

    f32x4 acc[3][2];
#pragma unroll
    for (int mi = 0; mi < 3; ++mi)
#pragma unroll
        for (int ni = 0; ni < 2; ++ni) acc[mi][ni] = (f32x4){0.f, 0.f, 0.f, 0.f};

    // B-frag loader for (stage st, channel-in-stage cL): 4 uint4 (ks x ni)
    auto bidx = [&](int st, int cL, int ks, int ni) -> size_t {
        int s = (kq * 32 + st * 4 + cL) * 2 + ks;
        return (size_t)(s * 8 + ntb + ni) * 64 + lane;
    };

    // stage 0 A
    ((float4*)&hs[0][0])[t] = hsg[t];
    if (t < 32) ((float4*)&hs[0][0])[256 + t] = hsg[256 + t];
    // prologue B (st0, cL0)
    uint4 bc0 = wp[bidx(0, 0, 0, 0)], bc1 = wp[bidx(0, 0, 0, 1)];
    uint4 bc2 = wp[bidx(0, 0, 1, 0)], bc3 = wp[bidx(0, 0, 1, 1)];
    __syncthreads();

    for (int st = 0; st < 8; ++st) {
        float4 pre0, pre1;
        bool more = (st < 7);
        if (more) {
            pre0 = hsg[(st + 1) * 288 + t];
            if (t < 32) pre1 = hsg[(st + 1) * 288 + 256 + t];
        }
        const unsigned short* buf = &hs[st & 1][0];
#pragma unroll
        for (int cL = 0; cL < 4; ++cL) {
            // prefetch next cL-group's B frags (last one reads harmless junk in-ws)
            int nst = (cL < 3) ? st : st + 1;
            int ncl = (cL < 3) ? cL + 1 : 0;
            bool pf = (nst < 8);
            uint4 bn0, bn1, bn2, bn3;
            if (pf) {
                bn0 = wp[bidx(nst, ncl, 0, 0)]; bn1 = wp[bidx(nst, ncl, 0, 1)];
                bn2 = wp[bidx(nst, ncl, 1, 0)]; bn3 = wp[bidx(nst, ncl, 1, 1)];
            }
            const unsigned short* cbuf = buf + cL * 576;
#pragma unroll
            for (int ks = 0; ks < 2; ++ks) {
                union { uint4 u; bf16x8 v; } bf0, bf1;
                bf0.u = ks ? bc2 : bc0;
                bf1.u = ks ? bc3 : bc1;
                int rowk = ks * 4 + quad;
#pragma unroll
                for (int mi = 0; mi < 3; ++mi) {
                    const unsigned int* ap =
                        (const unsigned int*)cbuf + (aoy2[mi] + rowk) * 12 + aox[mi];
                    union { unsigned int u[4]; bf16x8 v; } af;
                    af.u[0] = ap[0]; af.u[1] = ap[1]; af.u[2] = ap[2]; af.u[3] = ap[3];
                    acc[mi][0] = __builtin_amdgcn_mfma_f32_16x16x32_bf16(
                        af.v, bf0.v, acc[mi][0], 0, 0, 0);
                    acc[mi][1] = __builtin_amdgcn_mfma_f32_16x16x32_bf16(
                        af.v, bf1.v, acc[mi][1], 0, 0, 0);
                }
            }
            if (pf) { bc0 = bn0; bc1 = bn1; bc2 = bn2; bc3 = bn3; }
        }
        __syncthreads();
        if (more) {
            ((float4*)&hs[(st + 1) & 1][0])[t] = pre0;
            if (t < 32) ((float4*)&hs[(st + 1) & 1][0])[256 + t] = pre1;
        }
        __syncthreads();
    }

    // epilogue: plain coalesced stores to P_part[kq][b][p][n]
    float* pp = ws + PPART_OFF + ((size_t)(kq * 64 + b) * 81) * 128;
#pragma unroll
    for (int mi = 0; mi < 3; ++mi) {
#pragma unroll
        for (int ni = 0; ni < 2; ++ni) {
            int n = nh * 64 + (ng * 2 + ni) * 16 + m;
#pragma unroll
            for (int reg = 0; reg < 4; ++reg) {
                int p = (mg * 3 + mi) * 16 + quad * 4 + reg;
                if (p < 81) pp[(size_t)p * 128 + n] = acc[mi][ni][reg];
            }
        }
    }
}

// ------- squash: sum 8 kq partials + bias, squash over caps -> u_t --------
// grid 5184 = b*81+s ; block 128 (thread = prim channel n = i*16+d)
__global__ void k_squash_u(float* ws, const float* prim_b) {
    __shared__ float vs[128];
    __shared__ float fac[16];
    int blk = blockIdx.x;
    int b = blk / 81, s = blk % 81;
    int n = threadIdx.x;
    const float* pp = ws + PPART_OFF;
    float v = prim_b[n];
#pragma unroll
    for (int kq = 0; kq < 8; ++kq)
        v += pp[((size_t)(kq * 64 + b) * 81 + s) * 128 + n];
    vs[n] = v;
    __syncthreads();
    if (n < 16) {
        float sn = 0.f;
#pragma unroll
        for (int i = 0; i < 8; ++i) { float tv = vs[i * 16 + n]; sn += tv * tv; }
        fac[n] = sqrtf(sn) / (1.f + sn);
    }
    __syncthreads();
    int i = n >> 4, d = n & 15;
    ws[UT_OFF + ((size_t)(d * 81 + s) * 8 + i) * 64 + b] = v * fac[d];
}

// ------- s accumulation: sdst[b,c,o] += sum_n probs(n,c,b)*priors ---------
__global__ __launch_bounds__(256) void k_saccum(float* ws, const float* route_w,
                                                const float* probs, float* sdst) {
    __shared__ float wsl[10368];                     // 81n x 128(i,o) for fixed c
    int bx = blockIdx.x;                             // 43c x 16tile = 688
    int c = bx % 43, tile = bx / 43;
    int n0 = tile * 81;
    int t = threadIdx.x;
    for (int f = t; f < 10368; f += 256) {
        int row = f >> 7, col = f & 127;
        wsl[f] = route_w[((size_t)(n0 + row) * 43 + c) * 128 + col];
    }
    __syncthreads();
    int b = t & 63, og = t >> 6;
    const float* ut = ws + UT_OFF;
    float ax = 0.f, ay = 0.f, az = 0.f, aw = 0.f;
    for (int nl = 0; nl < 81; ++nl) {
        int n = n0 + nl;
        float pv = probs ? probs[((size_t)n * 43 + c) * 64 + b] : 1.0f;
#pragma unroll
        for (int i = 0; i < 8; ++i) {
            float uv = ut[(n * 8 + i) * 64 + b] * pv;
            float4 w4 = *(const float4*)(wsl + nl * 128 + i * 16 + og * 4);
            ax += uv * w4.x; ay += uv * w4.y; az += uv * w4.z; aw += uv * w4.w;
        }
    }
    float* dst = sdst + ((size_t)b * 43 + c) * 16 + og * 4;
    atomicAdd(dst + 0, ax); atomicAdd(dst + 1, ay);
    atomicAdd(dst + 2, az); atomicAdd(dst + 3, aw);
}

// -------- outputs = squash(s * scale), written transposed OUTT[c][o][b] ---
__global__ void k_outsquash(const float* s, float* ot, float scale) {
    int g = blockIdx.x * 256 + threadIdx.x;          // 11 blocks, 2752 tasks
    if (g >= 2752) return;
    int b = g / 43, c = g % 43;
    const float4* sp = (const float4*)(s + (size_t)g * 16);
    float v[16]; float sn = 0.f;
#pragma unroll
    for (int q = 0; q < 4; ++q) {
        float4 w = sp[q];
        v[q * 4] = w.x * scale; v[q * 4 + 1] = w.y * scale;
        v[q * 4 + 2] = w.z * scale; v[q * 4 + 3] = w.w * scale;
    }
#pragma unroll
    for (int j = 0; j < 16; ++j) sn += v[j] * v[j];
    float f = sqrtf(sn) / (1.f + sn);
#pragma unroll
    for (int j = 0; j < 16; ++j) ot[(size_t)(c * 16 + j) * 64 + b] = v[j] * f;
}

// ---- delta pass: L[n,c,b] (+)= sum_o priors(b,n,c,o)*outt(c,o,b) ---------
__global__ __launch_bounds__(256) void k_delta(float* ws, const float* route_w,
                                               const float* outt, float* L, int add) {
    __shared__ float wn[5504];                       // route_w[n] natural [c][i][o]
    __shared__ float us[512];                        // u[i][b]
    int n = blockIdx.x, t = threadIdx.x;             // 1296 blocks
    const float4* src = (const float4*)(route_w + (size_t)n * 5504);
    float4* dst4 = (float4*)wn;
    for (int f = t; f < 1376; f += 256) dst4[f] = src[f];
    const float* utn = ws + UT_OFF + (size_t)n * 512;
    us[t] = utn[t];
    us[t + 256] = utn[t + 256];
    __syncthreads();
    int b = t & 63, cg = t >> 6;
    float u[8];
#pragma unroll
    for (int i = 0; i < 8; ++i) u[i] = us[i * 64 + b];
    int c0 = cg * 11;
    int c1 = c0 + 11; if (c1 > 43) c1 = 43;
    for (int c = c0; c < c1; ++c) {
        float4 p0 = {0,0,0,0}, p1 = {0,0,0,0}, p2 = {0,0,0,0}, p3 = {0,0,0,0};
        const float4* wc = (const float4*)(wn + c * 128);
#pragma unroll
        for (int i = 0; i < 8; ++i) {
            float ui = u[i];
            float4 w0 = wc[i * 4 + 0], w1 = wc[i * 4 + 1],
                   w2 = wc[i * 4 + 2], w3 = wc[i * 4 + 3];
            p0.x += ui * w0.x; p0.y += ui * w0.y; p0.z += ui * w0.z; p0.w += ui * w0.w;
            p1.x += ui * w1.x; p1.y += ui * w1.y; p1.z += ui * w1.z; p1.w += ui * w1.w;
            p2.x += ui * w2.x; p2.y += ui * w2.y; p2.z += ui * w2.z; p2.w += ui * w2.w;
            p3.x += ui * w3.x; p3.y += ui * w3.y; p3.z += ui * w3.z; p3.w += ui * w3.w;
        }
        const float* ov = outt + (size_t)c * 1024 + b;   // OUTT[c][o][b]
        float val = p0.x * ov[0]      + p0.y * ov[64]   + p0.z * ov[128]  + p0.w * ov[192]
                  + p1.x * ov[256]    + p1.y * ov[320]  + p1.z * ov[384]  + p1.w * ov[448]
                  + p2.x * ov[512]    + p2.y * ov[576]  + p2.z * ov[640]  + p2.w * ov[704]
                  + p3.x * ov[768]    + p3.y * ov[832]  + p3.z * ov[896]  + p3.w * ov[960];
        size_t idx = ((size_t)n * 43 + c) * 64 + b;      // L[n][c][b] coalesced
        L[idx] = add ? (L[idx] + val) : val;
    }
}

// ------------- softmax over c: L[n,c,b] -> P[n,c,b] -----------------------
__global__ void k_softmax(const float* L, float* P) {
    int g = blockIdx.x * 256 + threadIdx.x;          // 324 blocks = 82944 = 1296n x 64b
    int n = g >> 6, b = g & 63;
    const float* lp = L + (size_t)n * 2752 + b;
    float v[43]; float m = -1e30f;
#pragma unroll
    for (int c = 0; c < 43; ++c) { v[c] = lp[c * 64]; m = fmaxf(m, v[c]); }
    float s = 0.f;
#pragma unroll
    for (int c = 0; c < 43; ++c) { v[c] = __expf(v[c] - m); s += v[c]; }
    float inv = 1.f / s;
    float* pp = P + (size_t)n * 2752 + b;
#pragma unroll
    for (int c = 0; c < 43; ++c) pp[c * 64] = v[c] * inv;
}

// ---------------- scores[b,c] = ||squash(s2)|| = sn/(1+sn) ----------------
__global__ void k_scores(const float* s2, float* out) {
    int g = blockIdx.x * 256 + threadIdx.x;
    if (g >= 2752) return;
    const float4* sp = (const float4*)(s2 + (size_t)g * 16);
    float sn = 0.f;
#pragma unroll
    for (int q = 0; q < 4; ++q) {
        float4 w = sp[q];
        sn += w.x * w.x + w.y * w.y + w.z * w.z + w.w * w.w;
    }
    out[g] = sn / (1.f + sn);
}

extern "C" void kernel_launch(void* const* d_in, const int* in_sizes, int n_in,
                              void* d_out, int out_size, void* d_ws, size_t ws_size,
                              hipStream_t stream) {
    const float* x  = (const float*)d_in[0];
    const float* w1 = (const float*)d_in[1];
    const float* b1 = (const float*)d_in[2];
    const float* w2 = (const float*)d_in[3];
    const float* b2 = (const float*)d_in[4];
    const float* rw = (const float*)d_in[5];
    float* ws  = (float*)d_ws;
    float* out = (float*)d_out;

    k_init      <<<860,  256, 0, stream>>>(ws);
    k_tr1       <<<243,  256, 0, stream>>>(ws, w1);
    k_pack2     <<<1024, 256, 0, stream>>>(ws, w2);
    k_conv1     <<<1536, 256, 0, stream>>>(ws, x, b1);
    k_conv2_mfma<<<1024, 256, 0, stream>>>(ws);
    k_squash_u  <<<5184, 128, 0, stream>>>(ws, b2);
    // iter 0: uniform probs (1/43 folded into squash scale)
    k_saccum   <<<688, 256, 0, stream>>>(ws, rw, nullptr, ws + S0_OFF);
    k_outsquash<<<11,  256, 0, stream>>>(ws + S0_OFF, ws + OUT0_OFF, 1.0f / 43.0f);
    k_delta    <<<1296,256, 0, stream>>>(ws, rw, ws + OUT0_OFF, ws + L_OFF, 0);
    // iter 1
    k_softmax  <<<324, 256, 0, stream>>>(ws + L_OFF, ws + PR_OFF);
    k_saccum   <<<688, 256, 0, stream>>>(ws, rw, ws + PR_OFF, ws + S1_OFF);
    k_outsquash<<<11,  256, 0, stream>>>(ws + S1_OFF, ws + OUT1_OFF, 1.0f);
    k_delta    <<<1296,256, 0, stream>>>(ws, rw, ws + OUT1_OFF, ws + L_OFF, 1);
    // iter 2
    k_softmax  <<<324, 256, 0, stream>>>(ws + L_OFF, ws + PR_OFF);
    k_saccum   <<<688, 256, 0, stream>>>(ws, rw, ws + PR_OFF, ws + S2_OFF);
    k_scores   <<<11,  256, 0, stream>>>(ws + S2_OFF, out);
}

// Round 5
// 321.887 us; speedup vs baseline: 3.6786x; 1.5404x over previous
//
#include <hip/hip_runtime.h>
#include <hip/hip_bf16.h>
#include <math.h>

// ---------------- workspace layout (float offsets) ----------------
// phase1: W1T | W2Tpk | H(bf16) | PPART          (all dead after squash_u)
// routing: PKW(@0) | L | PR alias the dead phase1 regions; UT + S persist
static constexpr size_t W1T_OFF  = 0;                // 62208
static constexpr size_t W2T_OFF  = 62208;            // 1048576 -> end 1110784
static constexpr size_t H_OFF    = 1110784;          // 4718592 -> end 5829376 (bf16 in float slots)
static constexpr size_t PPART_OFF= 5829376;          // 5308416 -> end 11137792
static constexpr size_t UT_OFF   = 11137792;         // 663552  -> end 11801344  u fp32 [n][b][i]
static constexpr size_t S0_OFF   = 11801344;
static constexpr size_t OUT0_OFF = 11845376;
static constexpr size_t S1_OFF   = 11889408;
static constexpr size_t OUT1_OFF = 11933440;
static constexpr size_t S2_OFF   = 11977472;         // -> end 12021504 floats = 48.1 MB
static constexpr size_t PKW_OFF  = 0;                // 3698688 (bf16 frags; after conv2)
static constexpr size_t L_OFF    = 3698688;          // 3566592 -> end 7265280 (dead H/PPART)
static constexpr size_t PR_OFF   = 7265280;          // 3566592 -> end 10831872 (dead PPART)

typedef __bf16 bf16x8 __attribute__((ext_vector_type(8)));
typedef float  f32x4  __attribute__((ext_vector_type(4)));

__device__ inline unsigned short f2bf(float f) {       // RNE fp32 -> bf16
    unsigned int u = __float_as_uint(f);
    u = (u + 0x7fffu + ((u >> 16) & 1u)) >> 16;
    return (unsigned short)u;
}
__device__ inline unsigned pk2(float a, float b) {     // packed RNE bf16 pair
    __hip_bfloat162 h = __float22bfloat162_rn(make_float2(a, b));
    return *(unsigned*)&h;
}

// ---------------- init: S0/OUT0/S1/OUT1/S2 <- 0 ---------------------------
__global__ void k_init(float* ws) {
    int g = blockIdx.x * 256 + threadIdx.x;          // 860*256 = 220160 exact
    ws[S0_OFF + g] = 0.f;
}

// ---------------- transpose conv1_w (256,243) -> W1T[243][256] ------------
__global__ void k_tr1(float* ws, const float* w1) {
    int g = blockIdx.x * 256 + threadIdx.x;          // 243*256 = 62208 exact
    int k = g >> 8, oc = g & 255;
    ws[W1T_OFF + g] = w1[oc * 243 + k];
}

// ---- pack prim_w (128 x 16384 fp32) -> bf16 MFMA B-fragment order --------
__global__ void k_pack2(float* ws, const float* w2) {
    int g = blockIdx.x * 256 + threadIdx.x;          // 1024 blocks -> 262144 exact
    int s = g >> 9;
    int r = g & 511;
    int nt = r >> 6, lane = r & 63;
    int n = nt * 16 + (lane & 15);
    int k0 = s * 32 + (lane >> 4) * 8;
    const float4* src = (const float4*)(w2 + (size_t)n * 16384 + k0);
    float4 v0 = src[0], v1 = src[1];
    uint4 o;
    o.x = pk2(v0.x, v0.y); o.y = pk2(v0.z, v0.w);
    o.z = pk2(v1.x, v1.y); o.w = pk2(v1.z, v1.w);
    ((uint4*)(ws + W2T_OFF))[g] = o;
}

// ---- pack route_w -> bf16 B-frags PKW[((c*16+tile)*21+ks)*64+lane] -------
// lane: quad=n-in-group, o=lane&15 ; 8 j-values = i=0..7
__global__ void k_packw(float* ws, const float* rw) {
    int g = blockIdx.x * 256 + threadIdx.x;          // 3612*256 = 924672 exact
    int lane = g & 63;
    int e = g >> 6;                                  // 14448 = 43 * 336
    int c = e / 336;
    int r = e % 336;
    int tile = r / 21, ks = r % 21;
    int quad = lane >> 4, o = lane & 15;
    int nl = ks * 4 + quad;
    uint4 out = {0u, 0u, 0u, 0u};
    if (nl < 81) {
        int n = tile * 81 + nl;
        const float* wp = rw + ((size_t)n * 43 + c) * 128 + o;
        out.x = pk2(wp[0],  wp[16]);
        out.y = pk2(wp[32], wp[48]);
        out.z = pk2(wp[64], wp[80]);
        out.w = pk2(wp[96], wp[112]);
    }
    ((uint4*)(ws + PKW_OFF))[g] = out;
}

// ---------------- conv1 9x9 VALID + bias + relu -> h (bf16, NCHW) ---------
__global__ __launch_bounds__(256) void k_conv1(float* ws, const float* x, const float* b1) {
    __shared__ float xs[864];                        // 3c x 9rows x 32
    int blk = blockIdx.x;                            // 64*24
    int b = blk / 24, oy = blk % 24;
    int t = threadIdx.x;
    for (int f = t; f < 864; f += 256) {
        int c = f / 288, r = (f >> 5) % 9, ix = f & 31;
        xs[f] = x[b * 3072 + c * 1024 + (oy + r) * 32 + ix];
    }
    __syncthreads();
    int oc = t;
    float acc[24];
    float bias = b1[oc];
#pragma unroll
    for (int j = 0; j < 24; ++j) acc[j] = bias;
    const float* w1t = ws + W1T_OFF;
    for (int c = 0; c < 3; ++c)
        for (int ky = 0; ky < 9; ++ky) {
            float xr[32];
            const float4* row4 = (const float4*)(xs + c * 288 + ky * 32);
#pragma unroll
            for (int q = 0; q < 8; ++q) {
                float4 v = row4[q];
                xr[q * 4] = v.x; xr[q * 4 + 1] = v.y; xr[q * 4 + 2] = v.z; xr[q * 4 + 3] = v.w;
            }
            int kbase = (c * 81 + ky * 9) * 256 + oc;
#pragma unroll
            for (int kx = 0; kx < 9; ++kx) {
                float w = w1t[kbase + kx * 256];
#pragma unroll
                for (int j = 0; j < 24; ++j) acc[j] += w * xr[j + kx];
            }
        }
    unsigned int* hp = (unsigned int*)((unsigned short*)(ws + H_OFF)
                        + ((size_t)(b * 256 + oc) * 576 + (size_t)oy * 24));
#pragma unroll
    for (int j = 0; j < 12; ++j) {
        float a0 = fmaxf(acc[2 * j], 0.f), a1 = fmaxf(acc[2 * j + 1], 0.f);
        hp[j] = pk2(a0, a1);
    }
}

// ------------- conv2 as implicit-im2col bf16 MFMA GEMM --------------------
// grid 1024 = 64 b x 8 kq x 2 nh ; block 256 (4 waves)
__global__ __launch_bounds__(256, 4) void k_conv2_mfma(float* ws) {
    __shared__ unsigned short hs[2][2304];           // 2 bufs x 4ch x 576
    int blk = blockIdx.x;
    int b  = blk >> 4;
    int kq = (blk >> 1) & 7;
    int nh = blk & 1;
    int t = threadIdx.x;
    int w = t >> 6, lane = t & 63;
    int quad = lane >> 4, m = lane & 15;
    int mg = w >> 1, ng = w & 1;

    int aoy2[3], aox[3];
#pragma unroll
    for (int mi = 0; mi < 3; ++mi) {
        int p = (mg * 3 + mi) * 16 + m;
        if (p > 80) p = 0;
        aoy2[mi] = (p / 9) * 2;
        aox[mi] = p % 9;
    }

    const float4* hsg = (const float4*)((const unsigned short*)(ws + H_OFF)
                         + (size_t)(b * 256 + kq * 32) * 576);
    const uint4* wp = (const uint4*)(ws + W2T_OFF);
    int ntb = nh * 4 + ng * 2;

    f32x4 acc[3][2];
#pragma unroll
    for (int mi = 0; mi < 3; ++mi)
#pragma unroll
        for (int ni = 0; ni < 2; ++ni) acc[mi][ni] = (f32x4){0.f, 0.f, 0.f, 0.f};

    auto bidx = [&](int st, int cL, int ks, int ni) -> size_t {
        int s = (kq * 32 + st * 4 + cL) * 2 + ks;
        return (size_t)(s * 8 + ntb + ni) * 64 + lane;
    };

    ((float4*)&hs[0][0])[t] = hsg[t];
    if (t < 32) ((float4*)&hs[0][0])[256 + t] = hsg[256 + t];
    uint4 bc0 = wp[bidx(0, 0, 0, 0)], bc1 = wp[bidx(0, 0, 0, 1)];
    uint4 bc2 = wp[bidx(0, 0, 1, 0)], bc3 = wp[bidx(0, 0, 1, 1)];
    __syncthreads();

    for (int st = 0; st < 8; ++st) {
        float4 pre0, pre1;
        bool more = (st < 7);
        if (more) {
            pre0 = hsg[(st + 1) * 288 + t];
            if (t < 32) pre1 = hsg[(st + 1) * 288 + 256 + t];
        }
        const unsigned short* buf = &hs[st & 1][0];
#pragma unroll
        for (int cL = 0; cL < 4; ++cL) {
            int nst = (cL < 3) ? st : st + 1;
            int ncl = (cL < 3) ? cL + 1 : 0;
            bool pf = (nst < 8);
            uint4 bn0, bn1, bn2, bn3;
            if (pf) {
                bn0 = wp[bidx(nst, ncl, 0, 0)]; bn1 = wp[bidx(nst, ncl, 0, 1)];
                bn2 = wp[bidx(nst, ncl, 1, 0)]; bn3 = wp[bidx(nst, ncl, 1, 1)];
            }
            const unsigned short* cbuf = buf + cL * 576;
#pragma unroll
            for (int ks = 0; ks < 2; ++ks) {
                union { uint4 u; bf16x8 v; } bf0, bf1;
                bf0.u = ks ? bc2 : bc0;
                bf1.u = ks ? bc3 : bc1;
                int rowk = ks * 4 + quad;
#pragma unroll
                for (int mi = 0; mi < 3; ++mi) {
                    const unsigned int* ap =
                        (const unsigned int*)cbuf + (aoy2[mi] + rowk) * 12 + aox[mi];
                    union { unsigned int u[4]; bf16x8 v; } af;
                    af.u[0] = ap[0]; af.u[1] = ap[1]; af.u[2] = ap[2]; af.u[3] = ap[3];
                    acc[mi][0] = __builtin_amdgcn_mfma_f32_16x16x32_bf16(
                        af.v, bf0.v, acc[mi][0], 0, 0, 0);
                    acc[mi][1] = __builtin_amdgcn_mfma_f32_16x16x32_bf16(
                        af.v, bf1.v, acc[mi][1], 0, 0, 0);
                }
            }
            if (pf) { bc0 = bn0; bc1 = bn1; bc2 = bn2; bc3 = bn3; }
        }
        __syncthreads();
        if (more) {
            ((float4*)&hs[(st + 1) & 1][0])[t] = pre0;
            if (t < 32) ((float4*)&hs[(st + 1) & 1][0])[256 + t] = pre1;
        }
        __syncthreads();
    }

    float* pp = ws + PPART_OFF + ((size_t)(kq * 64 + b) * 81) * 128;
#pragma unroll
    for (int mi = 0; mi < 3; ++mi) {
#pragma unroll
        for (int ni = 0; ni < 2; ++ni) {
            int n = nh * 64 + (ng * 2 + ni) * 16 + m;
#pragma unroll
            for (int reg = 0; reg < 4; ++reg) {
                int p = (mg * 3 + mi) * 16 + quad * 4 + reg;
                if (p < 81) pp[(size_t)p * 128 + n] = acc[mi][ni][reg];
            }
        }
    }
}

// ------- squash: sum 8 kq partials + bias -> u fp32 [n][b][i] -------------
// grid 5184 = b*81+s ; block 128 (thread = prim channel = i*16+d)
__global__ void k_squash_u(float* ws, const float* prim_b) {
    __shared__ float vs[128];
    __shared__ float fac[16];
    int blk = blockIdx.x;
    int b = blk / 81, s = blk % 81;
    int n = threadIdx.x;
    const float* pp = ws + PPART_OFF;
    float v = prim_b[n];
#pragma unroll
    for (int kq = 0; kq < 8; ++kq)
        v += pp[((size_t)(kq * 64 + b) * 81 + s) * 128 + n];
    vs[n] = v;
    __syncthreads();
    if (n < 16) {
        float sn = 0.f;
#pragma unroll
        for (int i = 0; i < 8; ++i) { float tv = vs[i * 16 + n]; sn += tv * tv; }
        fac[n] = sqrtf(sn) / (1.f + sn);
    }
    __syncthreads();
    int i = n >> 4, d = n & 15;
    ws[UT_OFF + ((size_t)(d * 81 + s) * 64 + b) * 8 + i] = v * fac[d];
}

// ------- s accumulation as MFMA GEMM: per c, s_c[b][o] over K=(n,i) -------
// grid 688 = 43c x 16tile ; block 256 = 4 waves (each one 16-b M-tile)
__global__ __launch_bounds__(256) void k_saccum_mfma(float* ws, const float* probs,
                                                     float* sdst) {
    int bx = blockIdx.x;
    int c = bx % 43, tile = bx / 43;
    int n0 = tile * 81;
    int t = threadIdx.x;
    int w = t >> 6, lane = t & 63;
    int quad = lane >> 4, m = lane & 15;
    int b = w * 16 + m;
    const float* ut = ws + UT_OFF;
    const uint4* pkw = (const uint4*)(ws + PKW_OFF)
                       + ((size_t)(c * 16 + tile) * 21) * 64 + lane;
    f32x4 acc = {0.f, 0.f, 0.f, 0.f};
#pragma unroll 7
    for (int ks = 0; ks < 21; ++ks) {
        int nl = ks * 4 + quad;
        union { uint4 u; bf16x8 v; } bf;
        bf.u = pkw[(size_t)ks * 64];
        union { unsigned u[4]; bf16x8 v; } af;
        af.u[0] = af.u[1] = af.u[2] = af.u[3] = 0u;
        if (nl < 81) {
            int n = n0 + nl;
            const float4* up = (const float4*)(ut + ((size_t)n * 64 + b) * 8);
            float4 u0 = up[0], u1 = up[1];
            float pv = probs ? probs[((size_t)n * 43 + c) * 64 + b] : 1.0f;
            af.u[0] = pk2(u0.x * pv, u0.y * pv);
            af.u[1] = pk2(u0.z * pv, u0.w * pv);
            af.u[2] = pk2(u1.x * pv, u1.y * pv);
            af.u[3] = pk2(u1.z * pv, u1.w * pv);
        }
        acc = __builtin_amdgcn_mfma_f32_16x16x32_bf16(af.v, bf.v, acc, 0, 0, 0);
    }
#pragma unroll
    for (int reg = 0; reg < 4; ++reg) {
        int bo = w * 16 + quad * 4 + reg;
        atomicAdd(sdst + ((size_t)bo * 43 + c) * 16 + m, acc[reg]);
    }
}

// -------- outputs = squash(s * scale), written transposed OUTT[c][o][b] ---
__global__ void k_outsquash(const float* s, float* ot, float scale) {
    int g = blockIdx.x * 256 + threadIdx.x;          // 11 blocks, 2752 tasks
    if (g >= 2752) return;
    int b = g / 43, c = g % 43;
    const float4* sp = (const float4*)(s + (size_t)g * 16);
    float v[16]; float sn = 0.f;
#pragma unroll
    for (int q = 0; q < 4; ++q) {
        float4 w = sp[q];
        v[q * 4] = w.x * scale; v[q * 4 + 1] = w.y * scale;
        v[q * 4 + 2] = w.z * scale; v[q * 4 + 3] = w.w * scale;
    }
#pragma unroll
    for (int j = 0; j < 16; ++j) sn += v[j] * v[j];
    float f = sqrtf(sn) / (1.f + sn);
#pragma unroll
    for (int j = 0; j < 16; ++j) ot[(size_t)(c * 16 + j) * 64 + b] = v[j] * f;
}

// ---- delta pass: L[n,c,b] (+)= sum_o priors(b,n,c,o)*outt(c,o,b) ---------
__global__ __launch_bounds__(256) void k_delta(float* ws, const float* route_w,
                                               const float* outt, float* L, int add) {
    __shared__ float wn[5504];                       // route_w[n] natural [c][i][o]
    int n = blockIdx.x, t = threadIdx.x;             // 1296 blocks
    const float4* src = (const float4*)(route_w + (size_t)n * 5504);
    float4* dst4 = (float4*)wn;
    for (int f = t; f < 1376; f += 256) dst4[f] = src[f];
    int b = t & 63, cg = t >> 6;
    const float4* up = (const float4*)(ws + UT_OFF + ((size_t)n * 64 + b) * 8);
    float4 ua = up[0], ub = up[1];
    float u[8] = {ua.x, ua.y, ua.z, ua.w, ub.x, ub.y, ub.z, ub.w};
    __syncthreads();
    int c0 = cg * 11;
    int c1 = c0 + 11; if (c1 > 43) c1 = 43;
    for (int c = c0; c < c1; ++c) {
        float4 p0 = {0,0,0,0}, p1 = {0,0,0,0}, p2 = {0,0,0,0}, p3 = {0,0,0,0};
        const float4* wc = (const float4*)(wn + c * 128);
#pragma unroll
        for (int i = 0; i < 8; ++i) {
            float ui = u[i];
            float4 w0 = wc[i * 4 + 0], w1 = wc[i * 4 + 1],
                   w2 = wc[i * 4 + 2], w3 = wc[i * 4 + 3];
            p0.x += ui * w0.x; p0.y += ui * w0.y; p0.z += ui * w0.z; p0.w += ui * w0.w;
            p1.x += ui * w1.x; p1.y += ui * w1.y; p1.z += ui * w1.z; p1.w += ui * w1.w;
            p2.x += ui * w2.x; p2.y += ui * w2.y; p2.z += ui * w2.z; p2.w += ui * w2.w;
            p3.x += ui * w3.x; p3.y += ui * w3.y; p3.z += ui * w3.z; p3.w += ui * w3.w;
        }
        const float* ov = outt + (size_t)c * 1024 + b;
        float val = p0.x * ov[0]      + p0.y * ov[64]   + p0.z * ov[128]  + p0.w * ov[192]
                  + p1.x * ov[256]    + p1.y * ov[320]  + p1.z * ov[384]  + p1.w * ov[448]
                  + p2.x * ov[512]    + p2.y * ov[576]  + p2.z * ov[640]  + p2.w * ov[704]
                  + p3.x * ov[768]    + p3.y * ov[832]  + p3.z * ov[896]  + p3.w * ov[960];
        size_t idx = ((size_t)n * 43 + c) * 64 + b;
        L[idx] = add ? (L[idx] + val) : val;
    }
}

// ------------- softmax over c: L[n,c,b] -> P[n,c,b] -----------------------
__global__ void k_softmax(const float* L, float* P) {
    int g = blockIdx.x * 256 + threadIdx.x;          // 324 blocks = 1296n x 64b
    int n = g >> 6, b = g & 63;
    const float* lp = L + (size_t)n * 2752 + b;
    float v[43]; float m = -1e30f;
#pragma unroll
    for (int c = 0; c < 43; ++c) { v[c] = lp[c * 64]; m = fmaxf(m, v[c]); }
    float s = 0.f;
#pragma unroll
    for (int c = 0; c < 43; ++c) { v[c] = __expf(v[c] - m); s += v[c]; }
    float inv = 1.f / s;
    float* pp = P + (size_t)n * 2752 + b;
#pragma unroll
    for (int c = 0; c < 43; ++c) pp[c * 64] = v[c] * inv;
}

// ---------------- scores[b,c] = ||squash(s2)|| = sn/(1+sn) ----------------
__global__ void k_scores(const float* s2, float* out) {
    int g = blockIdx.x * 256 + threadIdx.x;
    if (g >= 2752) return;
    const float4* sp = (const float4*)(s2 + (size_t)g * 16);
    float sn = 0.f;
#pragma unroll
    for (int q = 0; q < 4; ++q) {
        float4 w = sp[q];
        sn += w.x * w.x + w.y * w.y + w.z * w.z + w.w * w.w;
    }
    out[g] = sn / (1.f + sn);
}

extern "C" void kernel_launch(void* const* d_in, const int* in_sizes, int n_in,
                              void* d_out, int out_size, void* d_ws, size_t ws_size,
                              hipStream_t stream) {
    const float* x  = (const float*)d_in[0];
    const float* w1 = (const float*)d_in[1];
    const float* b1 = (const float*)d_in[2];
    const float* w2 = (const float*)d_in[3];
    const float* b2 = (const float*)d_in[4];
    const float* rw = (const float*)d_in[5];
    float* ws  = (float*)d_ws;
    float* out = (float*)d_out;

    k_init      <<<860,  256, 0, stream>>>(ws);
    k_tr1       <<<243,  256, 0, stream>>>(ws, w1);
    k_pack2     <<<1024, 256, 0, stream>>>(ws, w2);
    k_conv1     <<<1536, 256, 0, stream>>>(ws, x, b1);
    k_conv2_mfma<<<1024, 256, 0, stream>>>(ws);
    k_squash_u  <<<5184, 128, 0, stream>>>(ws, b2);
    k_packw     <<<3612, 256, 0, stream>>>(ws, rw);   // after conv2: overwrites W1T/W2T/H-head
    // iter 0: uniform probs (1/43 folded into squash scale)
    k_saccum_mfma<<<688, 256, 0, stream>>>(ws, nullptr, ws + S0_OFF);
    k_outsquash<<<11,  256, 0, stream>>>(ws + S0_OFF, ws + OUT0_OFF, 1.0f / 43.0f);
    k_delta    <<<1296,256, 0, stream>>>(ws, rw, ws + OUT0_OFF, ws + L_OFF, 0);
    // iter 1
    k_softmax  <<<324, 256, 0, stream>>>(ws + L_OFF, ws + PR_OFF);
    k_saccum_mfma<<<688, 256, 0, stream>>>(ws, ws + PR_OFF, ws + S1_OFF);
    k_outsquash<<<11,  256, 0, stream>>>(ws + S1_OFF, ws + OUT1_OFF, 1.0f);
    k_delta    <<<1296,256, 0, stream>>>(ws, rw, ws + OUT1_OFF, ws + L_OFF, 1);
    // iter 2
    k_softmax  <<<324, 256, 0, stream>>>(ws + L_OFF, ws + PR_OFF);
    k_saccum_mfma<<<688, 256, 0, stream>>>(ws, ws + PR_OFF, ws + S2_OFF);
    k_scores   <<<11,  256, 0, stream>>>(ws + S2_OFF, out);
}

// Round 6
// 290.226 us; speedup vs baseline: 4.0799x; 1.1091x over previous
//
#include <hip/hip_runtime.h>
#include <hip/hip_bf16.h>
#include <math.h>

// ---------------- workspace layout (float offsets) ----------------
// phase1: PKB(conv1 B-frags) | W2Tpk | H(bf16) | PPART   (dead after squash_u)
// routing: PKW(@0) | L | PR alias the dead phase1 regions; UT + S persist
static constexpr size_t W1T_OFF  = 0;                // PKB: 57344 floats (<62208)
static constexpr size_t W2T_OFF  = 62208;            // 1048576 -> end 1110784
static constexpr size_t H_OFF    = 1110784;          // 4718592 -> end 5829376 (bf16 in float slots)
static constexpr size_t PPART_OFF= 5829376;          // 5308416 -> end 11137792
static constexpr size_t UT_OFF   = 11137792;         // 663552  -> end 11801344  u fp32 [n][b][i]
static constexpr size_t S0_OFF   = 11801344;
static constexpr size_t OUT0_OFF = 11845376;
static constexpr size_t S1_OFF   = 11889408;
static constexpr size_t OUT1_OFF = 11933440;
static constexpr size_t S2_OFF   = 11977472;         // -> end 12021504 floats = 48.1 MB
static constexpr size_t PKW_OFF  = 0;                // 3698688 (bf16 frags; after conv2)
static constexpr size_t L_OFF    = 3698688;          // 3566592 -> end 7265280 (dead H/PPART)
static constexpr size_t PR_OFF   = 7265280;          // 3566592 -> end 10831872 (dead PPART)

typedef __bf16 bf16x8 __attribute__((ext_vector_type(8)));
typedef float  f32x4  __attribute__((ext_vector_type(4)));

__device__ inline unsigned pk2(float a, float b) {     // packed RNE bf16 pair
    __hip_bfloat162 h = __float22bfloat162_rn(make_float2(a, b));
    return *(unsigned*)&h;
}

// ---------------- init: S0/OUT0/S1/OUT1/S2 <- 0 ---------------------------
__global__ void k_init(float* ws) {
    int g = blockIdx.x * 256 + threadIdx.x;          // 860*256 = 220160 exact
    ws[S0_OFF + g] = 0.f;
}

// ---- pack conv1_w -> bf16 B-frags PKB[((ocq*14+s)*4+nt)*64+lane] ---------
// K layout: group g=c*9+ky (27, pad 28), kx padded 9->16; K-step s = groups (2s,2s+1)
// frag j -> k_local = quad*8+j ; gh=quad>>1, kx=(quad&1)*8+j
__global__ void k_packb1(float* ws, const float* w1) {
    int g = blockIdx.x * 256 + threadIdx.x;          // 56*256 = 14336 exact
    int lane = g & 63;
    int r = g >> 6;                                  // 224 = 4ocq * 14s * 4nt
    int nt = r & 3, s = (r >> 2) % 14, ocq = r / 56;
    int quad = lane >> 4;
    int oc = ocq * 64 + nt * 16 + (lane & 15);
    int grp = 2 * s + (quad >> 1);
    int kxb = (quad & 1) * 8;
    uint4 o = {0u, 0u, 0u, 0u};
    if (grp < 27) {
        const float* wp = w1 + (size_t)oc * 243 + grp * 9;
        float v[8];
#pragma unroll
        for (int j = 0; j < 8; ++j) {
            int kx = kxb + j;
            v[j] = (kx < 9) ? wp[kx] : 0.f;
        }
        o.x = pk2(v[0], v[1]); o.y = pk2(v[2], v[3]);
        o.z = pk2(v[4], v[5]); o.w = pk2(v[6], v[7]);
    }
    ((uint4*)(ws + W1T_OFF))[g] = o;
}

// ---- pack prim_w (128 x 16384 fp32) -> bf16 MFMA B-fragment order --------
__global__ void k_pack2(float* ws, const float* w2) {
    int g = blockIdx.x * 256 + threadIdx.x;          // 1024 blocks -> 262144 exact
    int s = g >> 9;
    int r = g & 511;
    int nt = r >> 6, lane = r & 63;
    int n = nt * 16 + (lane & 15);
    int k0 = s * 32 + (lane >> 4) * 8;
    const float4* src = (const float4*)(w2 + (size_t)n * 16384 + k0);
    float4 v0 = src[0], v1 = src[1];
    uint4 o;
    o.x = pk2(v0.x, v0.y); o.y = pk2(v0.z, v0.w);
    o.z = pk2(v1.x, v1.y); o.w = pk2(v1.z, v1.w);
    ((uint4*)(ws + W2T_OFF))[g] = o;
}

// ---- pack route_w -> bf16 B-frags PKW[((c*16+tile)*21+ks)*64+lane] -------
__global__ void k_packw(float* ws, const float* rw) {
    int g = blockIdx.x * 256 + threadIdx.x;          // 3612*256 = 924672 exact
    int lane = g & 63;
    int e = g >> 6;                                  // 14448 = 43 * 336
    int c = e / 336;
    int r = e % 336;
    int tile = r / 21, ks = r % 21;
    int quad = lane >> 4, o = lane & 15;
    int nl = ks * 4 + quad;
    uint4 out = {0u, 0u, 0u, 0u};
    if (nl < 81) {
        int n = tile * 81 + nl;
        const float* wp = rw + ((size_t)n * 43 + c) * 128 + o;
        out.x = pk2(wp[0],  wp[16]);
        out.y = pk2(wp[32], wp[48]);
        out.z = pk2(wp[64], wp[80]);
        out.w = pk2(wp[96], wp[112]);
    }
    ((uint4*)(ws + PKW_OFF))[g] = out;
}

// ------------- conv1 as implicit-im2col bf16 MFMA GEMM --------------------
// grid 256 = 64 b x 4 ocq (1 block/CU); block 4 waves
// wave: 9 M-tiles (p = (w*9+mt)*16+m, M=576) x 4 N-tiles (oc = ocq*64+nt*16+n)
// A[p][k]: k-group g=(c,ky) padded kx->16 ; frag = 8 contiguous x elems.
// x staged in LDS as TWO parity-shifted bf16 copies -> any start = 4 aligned dwords.
__global__ __launch_bounds__(256, 1) void k_conv1_mfma(float* ws, const float* x,
                                                       const float* b1) {
    __shared__ float xf[3136];                       // x[b] fp32 + zero pad
    __shared__ unsigned xd[2][1552];                 // dup bf16-pair copies
    int blk = blockIdx.x;
    int b = blk >> 2, ocq = blk & 3;
    int t = threadIdx.x;

    const float4* xg = (const float4*)(x + (size_t)b * 3072);
    float4* xf4 = (float4*)xf;
#pragma unroll
    for (int i = t; i < 784; i += 256)
        xf4[i] = (i < 768) ? xg[i] : make_float4(0.f, 0.f, 0.f, 0.f);
    __syncthreads();
    for (int i = t; i < 1552; i += 256) {
        float a0 = xf[2 * i], a1 = xf[2 * i + 1], a2 = xf[2 * i + 2];
        xd[0][i] = pk2(a0, a1);
        xd[1][i] = pk2(a1, a2);
    }
    __syncthreads();

    int w = t >> 6, lane = t & 63;
    int quad = lane >> 4, mrow = lane & 15;

    f32x4 acc[9][4];
#pragma unroll
    for (int mt = 0; mt < 9; ++mt)
#pragma unroll
        for (int nt = 0; nt < 4; ++nt) acc[mt][nt] = (f32x4){0.f, 0.f, 0.f, 0.f};

    int exo[9];                                      // oy*32 + ox + (quad&1)*8 per M-tile
#pragma unroll
    for (int mt = 0; mt < 9; ++mt) {
        int p = (w * 9 + mt) * 16 + mrow;
        exo[mt] = (p / 24) * 32 + (p % 24) + (quad & 1) * 8;
    }

    const uint4* pkb = (const uint4*)(ws + W1T_OFF) + (size_t)(ocq * 56) * 64;
    int gh = quad >> 1;

    for (int s = 0; s < 14; ++s) {
        int g = 2 * s + gh;
        int goff = (g < 27) ? (g / 9) * 1024 + (g % 9) * 32 : 0;  // c*1024+ky*32 (pad->0, B=0)
        uint4 bfr[4];
#pragma unroll
        for (int nt = 0; nt < 4; ++nt) bfr[nt] = pkb[(size_t)(s * 4 + nt) * 64 + lane];
        union { unsigned u[4]; bf16x8 v; } afr[9];
#pragma unroll
        for (int mt = 0; mt < 9; ++mt) {
            int e = goff + exo[mt];
            const unsigned* xp = &xd[e & 1][e >> 1];
            afr[mt].u[0] = xp[0]; afr[mt].u[1] = xp[1];
            afr[mt].u[2] = xp[2]; afr[mt].u[3] = xp[3];
        }
#pragma unroll
        for (int nt = 0; nt < 4; ++nt) {
            union { uint4 u; bf16x8 v; } bv; bv.u = bfr[nt];
#pragma unroll
            for (int mt = 0; mt < 9; ++mt)
                acc[mt][nt] = __builtin_amdgcn_mfma_f32_16x16x32_bf16(
                    afr[mt].v, bv.v, acc[mt][nt], 0, 0, 0);
        }
    }

    // epilogue: D[m=quad*4+reg][n=mrow]; bias+relu; packed dword stores
    unsigned short* hb = (unsigned short*)(ws + H_OFF);
#pragma unroll
    for (int nt = 0; nt < 4; ++nt) {
        int oc = ocq * 64 + nt * 16 + mrow;
        float bias = b1[oc];
        unsigned* hp = (unsigned*)(hb + (size_t)(b * 256 + oc) * 576);
#pragma unroll
        for (int mt = 0; mt < 9; ++mt) {
            int p = (w * 9 + mt) * 16 + quad * 4;
            float v0 = fmaxf(acc[mt][nt][0] + bias, 0.f);
            float v1 = fmaxf(acc[mt][nt][1] + bias, 0.f);
            float v2 = fmaxf(acc[mt][nt][2] + bias, 0.f);
            float v3 = fmaxf(acc[mt][nt][3] + bias, 0.f);
            hp[(p >> 1) + 0] = pk2(v0, v1);
            hp[(p >> 1) + 1] = pk2(v2, v3);
        }
    }
}

// ------------- conv2 as implicit-im2col bf16 MFMA GEMM --------------------
// grid 1024 = 64 b x 8 kq x 2 nh ; block 256 (4 waves)
__global__ __launch_bounds__(256, 4) void k_conv2_mfma(float* ws) {
    __shared__ unsigned short hs[2][2304];           // 2 bufs x 4ch x 576
    int blk = blockIdx.x;
    int b  = blk >> 4;
    int kq = (blk >> 1) & 7;
    int nh = blk & 1;
    int t = threadIdx.x;
    int w = t >> 6, lane = t & 63;
    int quad = lane >> 4, m = lane & 15;
    int mg = w >> 1, ng = w & 1;

    int aoy2[3], aox[3];
#pragma unroll
    for (int mi = 0; mi < 3; ++mi) {
        int p = (mg * 3 + mi) * 16 + m;
        if (p > 80) p = 0;
        aoy2[mi] = (p / 9) * 2;
        aox[mi] = p % 9;
    }

    const float4* hsg = (const float4*)((const unsigned short*)(ws + H_OFF)
                         + (size_t)(b * 256 + kq * 32) * 576);
    const uint4* wp = (const uint4*)(ws + W2T_OFF);
    int ntb = nh * 4 + ng * 2;

    f32x4 acc[3][2];
#pragma unroll
    for (int mi = 0; mi < 3; ++mi)
#pragma unroll
        for (int ni = 0; ni < 2; ++ni) acc[mi][ni] = (f32x4){0.f, 0.f, 0.f, 0.f};

    auto bidx = [&](int st, int cL, int ks, int ni) -> size_t {
        int s = (kq * 32 + st * 4 + cL) * 2 + ks;
        return (size_t)(s * 8 + ntb + ni) * 64 + lane;
    };

    ((float4*)&hs[0][0])[t] = hsg[t];
    if (t < 32) ((float4*)&hs[0][0])[256 + t] = hsg[256 + t];
    uint4 bc0 = wp[bidx(0, 0, 0, 0)], bc1 = wp[bidx(0, 0, 0, 1)];
    uint4 bc2 = wp[bidx(0, 0, 1, 0)], bc3 = wp[bidx(0, 0, 1, 1)];
    __syncthreads();

    for (int st = 0; st < 8; ++st) {
        float4 pre0, pre1;
        bool more = (st < 7);
        if (more) {
            pre0 = hsg[(st + 1) * 288 + t];
            if (t < 32) pre1 = hsg[(st + 1) * 288 + 256 + t];
        }
        const unsigned short* buf = &hs[st & 1][0];
#pragma unroll
        for (int cL = 0; cL < 4; ++cL) {
            int nst = (cL < 3) ? st : st + 1;
            int ncl = (cL < 3) ? cL + 1 : 0;
            bool pf = (nst < 8);
            uint4 bn0, bn1, bn2, bn3;
            if (pf) {
                bn0 = wp[bidx(nst, ncl, 0, 0)]; bn1 = wp[bidx(nst, ncl, 0, 1)];
                bn2 = wp[bidx(nst, ncl, 1, 0)]; bn3 = wp[bidx(nst, ncl, 1, 1)];
            }
            const unsigned short* cbuf = buf + cL * 576;
#pragma unroll
            for (int ks = 0; ks < 2; ++ks) {
                union { uint4 u; bf16x8 v; } bf0, bf1;
                bf0.u = ks ? bc2 : bc0;
                bf1.u = ks ? bc3 : bc1;
                int rowk = ks * 4 + quad;
#pragma unroll
                for (int mi = 0; mi < 3; ++mi) {
                    const unsigned int* ap =
                        (const unsigned int*)cbuf + (aoy2[mi] + rowk) * 12 + aox[mi];
                    union { unsigned int u[4]; bf16x8 v; } af;
                    af.u[0] = ap[0]; af.u[1] = ap[1]; af.u[2] = ap[2]; af.u[3] = ap[3];
                    acc[mi][0] = __builtin_amdgcn_mfma_f32_16x16x32_bf16(
                        af.v, bf0.v, acc[mi][0], 0, 0, 0);
                    acc[mi][1] = __builtin_amdgcn_mfma_f32_16x16x32_bf16(
                        af.v, bf1.v, acc[mi][1], 0, 0, 0);
                }
            }
            if (pf) { bc0 = bn0; bc1 = bn1; bc2 = bn2; bc3 = bn3; }
        }
        __syncthreads();
        if (more) {
            ((float4*)&hs[(st + 1) & 1][0])[t] = pre0;
            if (t < 32) ((float4*)&hs[(st + 1) & 1][0])[256 + t] = pre1;
        }
        __syncthreads();
    }

    float* pp = ws + PPART_OFF + ((size_t)(kq * 64 + b) * 81) * 128;
#pragma unroll
    for (int mi = 0; mi < 3; ++mi) {
#pragma unroll
        for (int ni = 0; ni < 2; ++ni) {
            int n = nh * 64 + (ng * 2 + ni) * 16 + m;
#pragma unroll
            for (int reg = 0; reg < 4; ++reg) {
                int p = (mg * 3 + mi) * 16 + quad * 4 + reg;
                if (p < 81) pp[(size_t)p * 128 + n] = acc[mi][ni][reg];
            }
        }
    }
}

// ------- squash: sum 8 kq partials + bias -> u fp32 [n][b][i] -------------
__global__ void k_squash_u(float* ws, const float* prim_b) {
    __shared__ float vs[128];
    __shared__ float fac[16];
    int blk = blockIdx.x;
    int b = blk / 81, s = blk % 81;
    int n = threadIdx.x;
    const float* pp = ws + PPART_OFF;
    float v = prim_b[n];
#pragma unroll
    for (int kq = 0; kq < 8; ++kq)
        v += pp[((size_t)(kq * 64 + b) * 81 + s) * 128 + n];
    vs[n] = v;
    __syncthreads();
    if (n < 16) {
        float sn = 0.f;
#pragma unroll
        for (int i = 0; i < 8; ++i) { float tv = vs[i * 16 + n]; sn += tv * tv; }
        fac[n] = sqrtf(sn) / (1.f + sn);
    }
    __syncthreads();
    int i = n >> 4, d = n & 15;
    ws[UT_OFF + ((size_t)(d * 81 + s) * 64 + b) * 8 + i] = v * fac[d];
}

// ------- s accumulation as MFMA GEMM: per c, s_c[b][o] over K=(n,i) -------
__global__ __launch_bounds__(256) void k_saccum_mfma(float* ws, const float* probs,
                                                     float* sdst) {
    int bx = blockIdx.x;
    int c = bx % 43, tile = bx / 43;
    int n0 = tile * 81;
    int t = threadIdx.x;
    int w = t >> 6, lane = t & 63;
    int quad = lane >> 4, m = lane & 15;
    int b = w * 16 + m;
    const float* ut = ws + UT_OFF;
    const uint4* pkw = (const uint4*)(ws + PKW_OFF)
                       + ((size_t)(c * 16 + tile) * 21) * 64 + lane;
    f32x4 acc = {0.f, 0.f, 0.f, 0.f};
#pragma unroll 7
    for (int ks = 0; ks < 21; ++ks) {
        int nl = ks * 4 + quad;
        union { uint4 u; bf16x8 v; } bf;
        bf.u = pkw[(size_t)ks * 64];
        union { unsigned u[4]; bf16x8 v; } af;
        af.u[0] = af.u[1] = af.u[2] = af.u[3] = 0u;
        if (nl < 81) {
            int n = n0 + nl;
            const float4* up = (const float4*)(ut + ((size_t)n * 64 + b) * 8);
            float4 u0 = up[0], u1 = up[1];
            float pv = probs ? probs[((size_t)n * 43 + c) * 64 + b] : 1.0f;
            af.u[0] = pk2(u0.x * pv, u0.y * pv);
            af.u[1] = pk2(u0.z * pv, u0.w * pv);
            af.u[2] = pk2(u1.x * pv, u1.y * pv);
            af.u[3] = pk2(u1.z * pv, u1.w * pv);
        }
        acc = __builtin_amdgcn_mfma_f32_16x16x32_bf16(af.v, bf.v, acc, 0, 0, 0);
    }
#pragma unroll
    for (int reg = 0; reg < 4; ++reg) {
        int bo = w * 16 + quad * 4 + reg;
        atomicAdd(sdst + ((size_t)bo * 43 + c) * 16 + m, acc[reg]);
    }
}

// -------- outputs = squash(s * scale), written transposed OUTT[c][o][b] ---
__global__ void k_outsquash(const float* s, float* ot, float scale) {
    int g = blockIdx.x * 256 + threadIdx.x;          // 11 blocks, 2752 tasks
    if (g >= 2752) return;
    int b = g / 43, c = g % 43;
    const float4* sp = (const float4*)(s + (size_t)g * 16);
    float v[16]; float sn = 0.f;
#pragma unroll
    for (int q = 0; q < 4; ++q) {
        float4 w = sp[q];
        v[q * 4] = w.x * scale; v[q * 4 + 1] = w.y * scale;
        v[q * 4 + 2] = w.z * scale; v[q * 4 + 3] = w.w * scale;
    }
#pragma unroll
    for (int j = 0; j < 16; ++j) sn += v[j] * v[j];
    float f = sqrtf(sn) / (1.f + sn);
#pragma unroll
    for (int j = 0; j < 16; ++j) ot[(size_t)(c * 16 + j) * 64 + b] = v[j] * f;
}

// ---- delta pass: L[n,c,b] (+)= sum_o priors(b,n,c,o)*outt(c,o,b) ---------
__global__ __launch_bounds__(256) void k_delta(float* ws, const float* route_w,
                                               const float* outt, float* L, int add) {
    __shared__ float wn[5504];                       // route_w[n] natural [c][i][o]
    int n = blockIdx.x, t = threadIdx.x;             // 1296 blocks
    const float4* src = (const float4*)(route_w + (size_t)n * 5504);
    float4* dst4 = (float4*)wn;
    for (int f = t; f < 1376; f += 256) dst4[f] = src[f];
    int b = t & 63, cg = t >> 6;
    const float4* up = (const float4*)(ws + UT_OFF + ((size_t)n * 64 + b) * 8);
    float4 ua = up[0], ub = up[1];
    float u[8] = {ua.x, ua.y, ua.z, ua.w, ub.x, ub.y, ub.z, ub.w};
    __syncthreads();
    int c0 = cg * 11;
    int c1 = c0 + 11; if (c1 > 43) c1 = 43;
    for (int c = c0; c < c1; ++c) {
        float4 p0 = {0,0,0,0}, p1 = {0,0,0,0}, p2 = {0,0,0,0}, p3 = {0,0,0,0};
        const float4* wc = (const float4*)(wn + c * 128);
#pragma unroll
        for (int i = 0; i < 8; ++i) {
            float ui = u[i];
            float4 w0 = wc[i * 4 + 0], w1 = wc[i * 4 + 1],
                   w2 = wc[i * 4 + 2], w3 = wc[i * 4 + 3];
            p0.x += ui * w0.x; p0.y += ui * w0.y; p0.z += ui * w0.z; p0.w += ui * w0.w;
            p1.x += ui * w1.x; p1.y += ui * w1.y; p1.z += ui * w1.z; p1.w += ui * w1.w;
            p2.x += ui * w2.x; p2.y += ui * w2.y; p2.z += ui * w2.z; p2.w += ui * w2.w;
            p3.x += ui * w3.x; p3.y += ui * w3.y; p3.z += ui * w3.z; p3.w += ui * w3.w;
        }
        const float* ov = outt + (size_t)c * 1024 + b;
        float val = p0.x * ov[0]      + p0.y * ov[64]   + p0.z * ov[128]  + p0.w * ov[192]
                  + p1.x * ov[256]    + p1.y * ov[320]  + p1.z * ov[384]  + p1.w * ov[448]
                  + p2.x * ov[512]    + p2.y * ov[576]  + p2.z * ov[640]  + p2.w * ov[704]
                  + p3.x * ov[768]    + p3.y * ov[832]  + p3.z * ov[896]  + p3.w * ov[960];
        size_t idx = ((size_t)n * 43 + c) * 64 + b;
        L[idx] = add ? (L[idx] + val) : val;
    }
}

// ------------- softmax over c: L[n,c,b] -> P[n,c,b] -----------------------
__global__ void k_softmax(const float* L, float* P) {
    int g = blockIdx.x * 256 + threadIdx.x;          // 324 blocks = 1296n x 64b
    int n = g >> 6, b = g & 63;
    const float* lp = L + (size_t)n * 2752 + b;
    float v[43]; float m = -1e30f;
#pragma unroll
    for (int c = 0; c < 43; ++c) { v[c] = lp[c * 64]; m = fmaxf(m, v[c]); }
    float s = 0.f;
#pragma unroll
    for (int c = 0; c < 43; ++c) { v[c] = __expf(v[c] - m); s += v[c]; }
    float inv = 1.f / s;
    float* pp = P + (size_t)n * 2752 + b;
#pragma unroll
    for (int c = 0; c < 43; ++c) pp[c * 64] = v[c] * inv;
}

// ---------------- scores[b,c] = ||squash(s2)|| = sn/(1+sn) ----------------
__global__ void k_scores(const float* s2, float* out) {
    int g = blockIdx.x * 256 + threadIdx.x;
    if (g >= 2752) return;
    const float4* sp = (const float4*)(s2 + (size_t)g * 16);
    float sn = 0.f;
#pragma unroll
    for (int q = 0; q < 4; ++q) {
        float4 w = sp[q];
        sn += w.x * w.x + w.y * w.y + w.z * w.z + w.w * w.w;
    }
    out[g] = sn / (1.f + sn);
}

extern "C" void kernel_launch(void* const* d_in, const int* in_sizes, int n_in,
                              void* d_out, int out_size, void* d_ws, size_t ws_size,
                              hipStream_t stream) {
    const float* x  = (const float*)d_in[0];
    const float* w1 = (const float*)d_in[1];
    const float* b1 = (const float*)d_in[2];
    const float* w2 = (const float*)d_in[3];
    const float* b2 = (const float*)d_in[4];
    const float* rw = (const float*)d_in[5];
    float* ws  = (float*)d_ws;
    float* out = (float*)d_out;

    k_init      <<<860,  256, 0, stream>>>(ws);
    k_packb1    <<<56,   256, 0, stream>>>(ws, w1);
    k_pack2     <<<1024, 256, 0, stream>>>(ws, w2);
    k_conv1_mfma<<<256,  256, 0, stream>>>(ws, x, b1);
    k_conv2_mfma<<<1024, 256, 0, stream>>>(ws);
    k_squash_u  <<<5184, 128, 0, stream>>>(ws, b2);
    k_packw     <<<3612, 256, 0, stream>>>(ws, rw);   // overwrites PKB/W2T/H-head (dead)
    // iter 0: uniform probs (1/43 folded into squash scale)
    k_saccum_mfma<<<688, 256, 0, stream>>>(ws, nullptr, ws + S0_OFF);
    k_outsquash<<<11,  256, 0, stream>>>(ws + S0_OFF, ws + OUT0_OFF, 1.0f / 43.0f);
    k_delta    <<<1296,256, 0, stream>>>(ws, rw, ws + OUT0_OFF, ws + L_OFF, 0);
    // iter 1
    k_softmax  <<<324, 256, 0, stream>>>(ws + L_OFF, ws + PR_OFF);
    k_saccum_mfma<<<688, 256, 0, stream>>>(ws, ws + PR_OFF, ws + S1_OFF);
    k_outsquash<<<11,  256, 0, stream>>>(ws + S1_OFF, ws + OUT1_OFF, 1.0f);
    k_delta    <<<1296,256, 0, stream>>>(ws, rw, ws + OUT1_OFF, ws + L_OFF, 1);
    // iter 2
    k_softmax  <<<324, 256, 0, stream>>>(ws + L_OFF, ws + PR_OFF);
    k_saccum_mfma<<<688, 256, 0, stream>>>(ws, ws + PR_OFF, ws + S2_OFF);
    k_scores   <<<11,  256, 0, stream>>>(ws + S2_OFF, out);
}